// Round 7
// baseline (257.336 us; speedup 1.0000x reference)
//
#include <hip/hip_runtime.h>

#pragma clang fp contract(off)

#define B 16
#define A 3
#define HGT 52
#define WID 52
#define HW 2704
#define NCAND 8112   // A*HW
#define CATTR 25
#define TOPK 2048
#define NWORD 64     // 64 u32 words x 32 bits = 2048 cols
#define CH 256       // rows per scan chunk
#define NCHUNK (TOPK / CH)   // 8
#define GPC (CH / 32)        // 8 groups per chunk
#define EPT 8        // sort: elements per thread

typedef unsigned int uint32;
typedef unsigned long long u64;

// ---------------- decode ----------------
// grid 507 x 256: exactly B*NCAND threads. LDS transpose so the 25-attr AoS
// output is stored as contiguous coalesced float4s (25600 B per block).
__global__ __launch_bounds__(256) void decode_kernel(const float* __restrict__ inp,
                                                     const float* __restrict__ anchors,
                                                     float* __restrict__ out,
                                                     float* __restrict__ cws) {
    __shared__ float sm[256 * CATTR];   // 25.6 KiB, candidate-major == out order
    int tid = threadIdx.x;
    int t = blockIdx.x * 256 + tid;     // < B*NCAND (129792 = 507*256 exactly)
    int b  = t / NCAND;
    int n  = t - b * NCAND;
    int a  = n / HW;
    int hw = n - a * HW;
    int gy = hw / WID;
    int gx = hw - gy * WID;
    const float* ip = inp + ((size_t)(b * (A * CATTR) + a * CATTR)) * HW + hw;
    float* sp = sm + tid * CATTR;

    float p0 = ip[0 * HW], p1 = ip[1 * HW], p2 = ip[2 * HW], p3 = ip[3 * HW], p4 = ip[4 * HW];
    float sx = 1.0f / (1.0f + expf(-p0));
    float sy = 1.0f / (1.0f + expf(-p1));
    float bx = (sx + (float)gx) * 8.0f;   // stride = 8 exactly
    float by = (sy + (float)gy) * 8.0f;
    float bw = expf(p2) * anchors[a * 2 + 0];   // (anchor/8)*8 exact
    float bh = expf(p3) * anchors[a * 2 + 1];
    float cf = 1.0f / (1.0f + expf(-p4));
    sp[0] = bx; sp[1] = by; sp[2] = bw; sp[3] = bh; sp[4] = cf;
    cws[t] = cf;   // contiguous conf for the sort
#pragma unroll
    for (int c = 0; c < 20; ++c) {
        float v = ip[(5 + c) * HW];
        sp[5 + c] = 1.0f / (1.0f + expf(-v));
    }
    __syncthreads();
    // coalesced store: 6400 floats = 1600 float4 per block
    const float4* sm4 = (const float4*)sm;
    float4* o4 = (float4*)(out + (size_t)blockIdx.x * 256 * CATTR);
#pragma unroll
    for (int k = 0; k < 6; ++k) o4[k * 256 + tid] = sm4[k * 256 + tid];
    if (tid < 64) o4[1536 + tid] = sm4[1536 + tid];
}

// ---------------- sort helpers ----------------
// key = (~(conf_bits|sign) << 32) | idx ; ascending == conf desc, idx asc.
__device__ __forceinline__ void cexd(u64& a, u64& b, bool up) {
    if ((a > b) == up) { u64 tmp = a; a = b; b = tmp; }
}

__device__ __forceinline__ u64 sel(u64 k, u64 o, bool kmin) {
    return kmin ? (k < o ? k : o) : (k > o ? k : o);
}

// bitonic merge of a 2048-element bitonic sequence to ascending order.
__device__ __forceinline__ void bitonic_merge_2048(u64 key[EPT], u64* mb, int t) {
    for (unsigned j = 1024; j >= 8; j >>= 1) {
        unsigned m = j >> 3;
        bool kmin = ((t & m) == 0);
        if (m >= 64) {
            __syncthreads();
#pragma unroll
            for (int e = 0; e < EPT; ++e) mb[e * 256 + t] = key[e];
            __syncthreads();
            int pt = t ^ (int)m;
#pragma unroll
            for (int e = 0; e < EPT; ++e) key[e] = sel(key[e], mb[e * 256 + pt], kmin);
        } else {
#pragma unroll
            for (int e = 0; e < EPT; ++e) {
                u64 o = __shfl_xor(key[e], (int)m);
                key[e] = sel(key[e], o, kmin);
            }
        }
    }
    cexd(key[0], key[4], true); cexd(key[1], key[5], true);
    cexd(key[2], key[6], true); cexd(key[3], key[7], true);
    cexd(key[0], key[2], true); cexd(key[1], key[3], true);
    cexd(key[4], key[6], true); cexd(key[5], key[7], true);
    cexd(key[0], key[1], true); cexd(key[2], key[3], true);
    cexd(key[4], key[5], true); cexd(key[6], key[7], true);
}

// ---------------- S1: sort each 2048-chunk ascending ----------------
__global__ __launch_bounds__(256) void sort1_kernel(const float* __restrict__ conf,
                                                    u64* __restrict__ runs) {
    __shared__ u64 mb[2048];   // 16 KiB SoA mailbox
    int blk = blockIdx.x;
    int b = blk >> 2, c = blk & 3;
    int t = threadIdx.x;
    int base = t * EPT;               // local 0..2047
    int gbase = c * 2048 + base;      // candidate index in batch
    const float* cp = conf + b * NCAND;

    u64 key[EPT];
    if (gbase + EPT <= NCAND) {
        const float4* cp4 = (const float4*)(cp + gbase);
        float4 c0 = cp4[0], c1 = cp4[1];
        float cf[EPT] = {c0.x, c0.y, c0.z, c0.w, c1.x, c1.y, c1.z, c1.w};
#pragma unroll
        for (int e = 0; e < EPT; ++e) {
            unsigned bits = __float_as_uint(cf[e]) | 0x80000000u;
            key[e] = ((u64)(~bits) << 32) | (unsigned)(gbase + e);
        }
    } else {
#pragma unroll
        for (int e = 0; e < EPT; ++e) {
            int idx = gbase + e;
            if (idx < NCAND) {
                unsigned bits = __float_as_uint(cp[idx]) | 0x80000000u;
                key[e] = ((u64)(~bits) << 32) | (unsigned)idx;
            } else key[e] = ~0ull;   // pad sorts last
        }
    }

    cexd(key[0], key[1], true); cexd(key[2], key[3], false);
    cexd(key[4], key[5], true); cexd(key[6], key[7], false);

    cexd(key[0], key[2], true);  cexd(key[1], key[3], true);
    cexd(key[4], key[6], false); cexd(key[5], key[7], false);
    cexd(key[0], key[1], true);  cexd(key[2], key[3], true);
    cexd(key[4], key[5], false); cexd(key[6], key[7], false);

    bool up8 = ((t & 1) == 0);
    cexd(key[0], key[4], up8); cexd(key[1], key[5], up8);
    cexd(key[2], key[6], up8); cexd(key[3], key[7], up8);
    cexd(key[0], key[2], up8); cexd(key[1], key[3], up8);
    cexd(key[4], key[6], up8); cexd(key[5], key[7], up8);
    cexd(key[0], key[1], up8); cexd(key[2], key[3], up8);
    cexd(key[4], key[5], up8); cexd(key[6], key[7], up8);

    for (unsigned k = 16; k <= 2048; k <<= 1) {
        bool up = (((unsigned)base & k) == 0);
        for (unsigned j = k >> 1; j >= 8; j >>= 1) {
            unsigned m = j >> 3;
            bool kmin = (up == ((t & m) == 0));
            if (m >= 64) {
                __syncthreads();
#pragma unroll
                for (int e = 0; e < EPT; ++e) mb[e * 256 + t] = key[e];
                __syncthreads();
                int pt = t ^ (int)m;
#pragma unroll
                for (int e = 0; e < EPT; ++e) key[e] = sel(key[e], mb[e * 256 + pt], kmin);
            } else {
#pragma unroll
                for (int e = 0; e < EPT; ++e) {
                    u64 o = __shfl_xor(key[e], (int)m);
                    key[e] = sel(key[e], o, kmin);
                }
            }
        }
        cexd(key[0], key[4], up); cexd(key[1], key[5], up);
        cexd(key[2], key[6], up); cexd(key[3], key[7], up);
        cexd(key[0], key[2], up); cexd(key[1], key[3], up);
        cexd(key[4], key[6], up); cexd(key[5], key[7], up);
        cexd(key[0], key[1], up); cexd(key[2], key[3], up);
        cexd(key[4], key[5], up); cexd(key[6], key[7], up);
    }

    u64* R = runs + ((size_t)b * 4 + c) * 2048;
#pragma unroll
    for (int e = 0; e < EPT; ++e) R[base + e] = key[e];
}

// ---------------- S2: merge+prune two 2048-runs -> sorted 2048 -------
__global__ __launch_bounds__(256) void sort2_kernel(const u64* __restrict__ runs,
                                                    u64* __restrict__ half) {
    __shared__ u64 mb[2048];
    int blk = blockIdx.x;
    int b = blk >> 1, p = blk & 1;
    int t = threadIdx.x;
    int base = t * EPT;
    const u64* Av = runs + ((size_t)b * 4 + p * 2) * 2048;
    const u64* Bv = Av + 2048;

    u64 key[EPT];
#pragma unroll
    for (int e = 0; e < EPT; ++e) {
        u64 a = Av[base + e];
        u64 o = Bv[2047 - (base + e)];
        key[e] = a < o ? a : o;
    }
    bitonic_merge_2048(key, mb, t);
    u64* H = half + ((size_t)b * 2 + p) * 2048;
#pragma unroll
    for (int e = 0; e < EPT; ++e) H[base + e] = key[e];
}

// ---------------- S3: final merge+prune -> topf + fused geometry ---------
__global__ __launch_bounds__(256) void sort3_kernel(const u64* __restrict__ half,
                                                    const float* __restrict__ out,
                                                    float* __restrict__ topf,
                                                    float* __restrict__ gx1,
                                                    float* __restrict__ gy1,
                                                    float* __restrict__ gx2,
                                                    float* __restrict__ gy2,
                                                    float* __restrict__ gar,
                                                    uint32* __restrict__ gcv,
                                                    uint32* __restrict__ vwords) {
    __shared__ u64 mb[2048];
    __shared__ uint32 vb[256];
    int b = blockIdx.x;
    int t = threadIdx.x;
    int base = t * EPT;
    const u64* Av = half + (size_t)b * 2 * 2048;
    const u64* Bv = Av + 2048;

    u64 key[EPT];
#pragma unroll
    for (int e = 0; e < EPT; ++e) {
        u64 a = Av[base + e];
        u64 o = Bv[2047 - (base + e)];
        key[e] = a < o ? a : o;
    }
    bitonic_merge_2048(key, mb, t);

    const float* ob = out + (size_t)b * NCAND * CATTR;
    uint32 vbits = 0;
#pragma unroll
    for (int e = 0; e < EPT; ++e) {
        uint32 idx = (uint32)(key[e] & 0xFFFFFFFFu);
        int tg = b * TOPK + base + e;
        topf[tg] = (float)idx;
        const float* p = ob + (size_t)idx * CATTR;
        float cx = p[0], cy = p[1], w = p[2], h = p[3], cf = p[4];
        float hw_ = w * 0.5f, hh_ = h * 0.5f;  // w/2 exact
        float x1 = cx - hw_, y1 = cy - hh_, x2 = cx + hw_, y2 = cy + hh_;
        gx1[tg] = x1; gy1[tg] = y1; gx2[tg] = x2; gy2[tg] = y2;
        gar[tg] = ((x2 - x1) + 1.0f) * ((y2 - y1) + 1.0f);
        float best = p[5]; int bc = 0;
#pragma unroll
        for (int c = 1; c < 20; ++c) {      // first-max argmax (numpy semantics)
            float v = p[5 + c];
            if (v > best) { best = v; bc = c; }
        }
        gcv[tg] = (uint32)bc;
        vbits |= (cf >= 0.5f ? 1u : 0u) << e;
    }
    vb[t] = vbits;
    __syncthreads();
    if (t < 64) {
        uint32 w4 = vb[t * 4] | (vb[t * 4 + 1] << 8) | (vb[t * 4 + 2] << 16) | (vb[t * 4 + 3] << 24);
        vwords[b * 64 + t] = w4;
    }
}

// ---------------- NMS stage 2: suppression bitmask build ----------------
// Strict-upper-triangle only (bits j<=i left unwritten: provably never
// consumed by scan). Block = strip pair (p, 31-p) -> constant 33 rounds.
// Exact div-free IoU threshold (see R5 proof).
#define KMID (13421772.5 / 33554432.0)
__global__ __launch_bounds__(1024) void build_kernel(const float* __restrict__ gx1,
                                                     const float* __restrict__ gy1,
                                                     const float* __restrict__ gx2,
                                                     const float* __restrict__ gy2,
                                                     const float* __restrict__ gar,
                                                     const uint32* __restrict__ gcv,
                                                     uint32* __restrict__ rowmask) {
    __shared__ float4 x4s[TOPK];    // 32 KiB
    __shared__ float  ars[TOPK];    // 8 KiB
    __shared__ uint32 clss[TOPK];   // 8 KiB
    int bt   = blockIdx.y;
    int pr   = blockIdx.x;          // pair 0..15
    int tid  = threadIdx.x;
    int lane = tid & 63;
    int wvq  = tid >> 6;            // row-quad 0..15
    int base = bt * TOPK;
    u64* rm64 = (u64*)(rowmask + (size_t)base * NWORD);   // [row][32] u64

    for (int j = tid; j < TOPK; j += 1024) {
        int g = base + j;
        x4s[j]  = make_float4(gx1[g], gy1[g], gx2[g], gy2[g]);
        ars[j]  = gar[g];
        clss[j] = gcv[g] & 0xffu;
    }
    __syncthreads();

#pragma unroll
    for (int s = 0; s < 2; ++s) {
        int r = s ? (31 - pr) : pr;         // strip index
        int i0 = r * 64 + wvq * 4;          // this wave's 4 rows
        float4 rq[4]; float rar4[4]; uint32 rcl4[4];
#pragma unroll
        for (int k = 0; k < 4; ++k) {
            rq[k] = x4s[i0 + k]; rar4[k] = ars[i0 + k]; rcl4[k] = clss[i0 + k];
        }
        for (int cg = r; cg < 32; ++cg) {
            int j = cg * 64 + lane;
            float4 c  = x4s[j];
            float car = ars[j];
            uint32 cc = clss[j];
            u64 bal[4];
#pragma unroll
            for (int k = 0; k < 4; ++k) {
                float ix1 = fmaxf(rq[k].x, c.x);
                float iy1 = fmaxf(rq[k].y, c.y);
                float ix2 = fminf(rq[k].z, c.z);
                float iy2 = fminf(rq[k].w, c.w);
                float iw = fmaxf((ix2 - ix1) + 1.0f, 0.0f);
                float ih = fmaxf((iy2 - iy1) + 1.0f, 0.0f);
                float inter = iw * ih;
                float denom = ((rar4[k] + car) - inter) + 1e-16f;
                bool cond = ((double)inter > KMID * (double)denom) && (cc == rcl4[k]);
                bal[k] = __ballot(cond);
            }
            u64 v = bal[0];
            if (lane == 1) v = bal[1];
            if (lane == 2) v = bal[2];
            if (lane == 3) v = bal[3];
            if (lane < 4) rm64[(size_t)(i0 + lane) * 32 + cg] = v;
        }
    }
}

// ---------------- NMS stage 3: group-batched greedy scan ----------------
// 1 block/batch, 1024 thr. Wave 0 scans; waves 1-15 stream 64 KiB chunks
// into a double-buffered LDS. Per 32-candidate group: broadcast-read 32
// self words (same-address LDS = free), resolve 32 keep bits in-register
// (pure VALU serial chain), then OR full rows into supp ONLY for kept
// candidates (lane-consecutive LDS reads, keep_mask lane-uniform).
// Validity folded into supp init (supp = ~vword). One shfl per group.
// Garbage bits at j<=i (triangle build/poison) provably never consumed.
__global__ __launch_bounds__(1024) void scan_kernel(const uint32* __restrict__ rowmask,
                                                    const uint32* __restrict__ vwords,
                                                    float* __restrict__ keepf) {
    __shared__ uint32 buf[2][CH * NWORD];   // 2 x 64 KiB
    int bt  = blockIdx.x;
    int tid = threadIdx.x;
    int wv  = tid >> 6;
    int l   = tid & 63;
    const uint32* rm = rowmask + (size_t)bt * TOPK * NWORD;

    if (wv > 0) {
        int ctid = tid - 64;
        const uint4* src = (const uint4*)rm;
        uint4* dst = (uint4*)buf[0];
        for (int o = ctid; o < CH * NWORD / 4; o += 960) dst[o] = src[o];
    }
    uint32 supp = 0, keepw = 0;
    if (wv == 0) supp = ~vwords[bt * 64 + l];
    __syncthreads();

    for (int c = 0; c < NCHUNK; ++c) {
        if (wv > 0) {
            if (c + 1 < NCHUNK) {
                int ctid = tid - 64;
                const uint4* src = (const uint4*)(rm + (size_t)(c + 1) * CH * NWORD);
                uint4* dst = (uint4*)buf[(c + 1) & 1];
                for (int o = ctid; o < CH * NWORD / 4; o += 960) dst[o] = src[o];
            }
        } else {
            const uint32* bp = buf[c & 1];
            uint32 sw[32];
#pragma unroll
            for (int k = 0; k < 32; ++k) sw[k] = bp[k * NWORD + c * GPC];  // group 0 self words
            for (int gl = 0; gl < GPC; ++gl) {
                int g = c * GPC + gl;
                uint32 cur = __shfl(supp, g);
                uint32 keep = 0;
#pragma unroll
                for (int k = 0; k < 32; ++k) {
                    uint32 bitk = (cur >> k) & 1u;
                    keep |= (bitk ^ 1u) << k;
                    cur |= sw[k] & (bitk - 1u);   // bitk=0 -> all-ones mask
                }
                if (l == g) keepw = keep;
                if (gl + 1 < GPC) {               // prefetch next group's self words
#pragma unroll
                    for (int k = 0; k < 32; ++k) sw[k] = bp[((gl + 1) * 32 + k) * NWORD + (g + 1)];
                }
                uint32 rows = keep, upd = 0;      // keep is lane-uniform: no divergence
                while (rows) {
                    int k = __builtin_ctz(rows); rows &= rows - 1;
                    upd |= bp[(gl * 32 + k) * NWORD + l];
                }
                supp |= upd;
            }
        }
        __syncthreads();
    }

    if (wv == 0) {
#pragma unroll
        for (int k = 0; k < 32; ++k)
            keepf[bt * TOPK + l * 32 + k] = (float)((keepw >> k) & 1u);
    }
}

extern "C" void kernel_launch(void* const* d_in, const int* in_sizes, int n_in,
                              void* d_out, int out_size, void* d_ws, size_t ws_size,
                              hipStream_t stream) {
    const float* inp     = (const float*)d_in[0];
    const float* anchors = (const float*)d_in[1];
    float* out   = (float*)d_out;                        // [B, N, 25]
    float* topf  = out  + (size_t)B * NCAND * CATTR;     // [B, 2048] indices as float
    float* keepf = topf + (size_t)B * TOPK;              // [B, 2048] 0/1 as float

    // workspace layout
    float*  cws = (float*)d_ws;                          // [B, NCAND] conf
    float*  gx1 = cws + B * NCAND;
    float*  gy1 = gx1 + B * TOPK;
    float*  gx2 = gy1 + B * TOPK;
    float*  gy2 = gx2 + B * TOPK;
    float*  gar = gy2 + B * TOPK;
    uint32* gcv = (uint32*)(gar + B * TOPK);
    uint32* rowmask = gcv + B * TOPK;                    // 16*2048*64 u32 = 8 MiB
    uint32* vwords  = rowmask + (size_t)B * TOPK * NWORD;
    // sort scratch aliases onto rowmask (sort completes before build writes)
    u64* runs = (u64*)rowmask;                           // 1 MiB
    u64* half = runs + (size_t)B * 4 * 2048;             // 0.5 MiB

    decode_kernel<<<(B * NCAND) / 256, 256, 0, stream>>>(inp, anchors, out, cws);
    sort1_kernel<<<B * 4, 256, 0, stream>>>(cws, runs);
    sort2_kernel<<<B * 2, 256, 0, stream>>>(runs, half);
    sort3_kernel<<<B, 256, 0, stream>>>(half, out, topf, gx1, gy1, gx2, gy2, gar, gcv, vwords);
    build_kernel<<<dim3(16, B), 1024, 0, stream>>>(gx1, gy1, gx2, gy2, gar, gcv, rowmask);
    scan_kernel<<<B, 1024, 0, stream>>>(rowmask, vwords, keepf);
}

// Round 8
// 220.296 us; speedup vs baseline: 1.1681x; 1.1681x over previous
//
#include <hip/hip_runtime.h>

#pragma clang fp contract(off)

#define B 16
#define A 3
#define HGT 52
#define WID 52
#define HW 2704
#define NCAND 8112   // A*HW
#define CATTR 25
#define TOPK 2048
#define NWORD 64     // 64 u32 words x 32 bits = 2048 cols
#define CH 256       // rows per scan chunk
#define NCHUNK (TOPK / CH)   // 8
#define GPC (CH / 32)        // 8 groups per chunk
#define EPT 8        // sort: elements per thread

typedef unsigned int uint32;
typedef unsigned long long u64;

// ---------------- decode ----------------
// grid 507 x 256: exactly B*NCAND threads. LDS transpose so the 25-attr AoS
// output is stored as contiguous coalesced float4s.
__global__ __launch_bounds__(256) void decode_kernel(const float* __restrict__ inp,
                                                     const float* __restrict__ anchors,
                                                     float* __restrict__ out,
                                                     float* __restrict__ cws) {
    __shared__ float sm[256 * CATTR];   // 25.6 KiB, candidate-major == out order
    int tid = threadIdx.x;
    int t = blockIdx.x * 256 + tid;     // < B*NCAND (129792 = 507*256 exactly)
    int b  = t / NCAND;
    int n  = t - b * NCAND;
    int a  = n / HW;
    int hw = n - a * HW;
    int gy = hw / WID;
    int gx = hw - gy * WID;
    const float* ip = inp + ((size_t)(b * (A * CATTR) + a * CATTR)) * HW + hw;
    float* sp = sm + tid * CATTR;

    float p0 = ip[0 * HW], p1 = ip[1 * HW], p2 = ip[2 * HW], p3 = ip[3 * HW], p4 = ip[4 * HW];
    float sx = 1.0f / (1.0f + expf(-p0));
    float sy = 1.0f / (1.0f + expf(-p1));
    float bx = (sx + (float)gx) * 8.0f;   // stride = 8 exactly
    float by = (sy + (float)gy) * 8.0f;
    float bw = expf(p2) * anchors[a * 2 + 0];   // (anchor/8)*8 exact
    float bh = expf(p3) * anchors[a * 2 + 1];
    float cf = 1.0f / (1.0f + expf(-p4));
    sp[0] = bx; sp[1] = by; sp[2] = bw; sp[3] = bh; sp[4] = cf;
    cws[t] = cf;   // contiguous conf for the sort
#pragma unroll
    for (int c = 0; c < 20; ++c) {
        float v = ip[(5 + c) * HW];
        sp[5 + c] = 1.0f / (1.0f + expf(-v));
    }
    __syncthreads();
    const float4* sm4 = (const float4*)sm;
    float4* o4 = (float4*)(out + (size_t)blockIdx.x * 256 * CATTR);
#pragma unroll
    for (int k = 0; k < 6; ++k) o4[k * 256 + tid] = sm4[k * 256 + tid];
    if (tid < 64) o4[1536 + tid] = sm4[1536 + tid];
}

// ---------------- sort helpers ----------------
// key = (~(conf_bits|sign) << 32) | idx ; ascending == conf desc, idx asc.
__device__ __forceinline__ void cexd(u64& a, u64& b, bool up) {
    if ((a > b) == up) { u64 tmp = a; a = b; b = tmp; }
}

__device__ __forceinline__ u64 sel(u64 k, u64 o, bool kmin) {
    return kmin ? (k < o ? k : o) : (k > o ? k : o);
}

// bitonic merge of a 2048-element bitonic sequence to ascending order.
__device__ __forceinline__ void bitonic_merge_2048(u64 key[EPT], u64* mb, int t) {
    for (unsigned j = 1024; j >= 8; j >>= 1) {
        unsigned m = j >> 3;
        bool kmin = ((t & m) == 0);
        if (m >= 64) {
            __syncthreads();
#pragma unroll
            for (int e = 0; e < EPT; ++e) mb[e * 256 + t] = key[e];
            __syncthreads();
            int pt = t ^ (int)m;
#pragma unroll
            for (int e = 0; e < EPT; ++e) key[e] = sel(key[e], mb[e * 256 + pt], kmin);
        } else {
#pragma unroll
            for (int e = 0; e < EPT; ++e) {
                u64 o = __shfl_xor(key[e], (int)m);
                key[e] = sel(key[e], o, kmin);
            }
        }
    }
    cexd(key[0], key[4], true); cexd(key[1], key[5], true);
    cexd(key[2], key[6], true); cexd(key[3], key[7], true);
    cexd(key[0], key[2], true); cexd(key[1], key[3], true);
    cexd(key[4], key[6], true); cexd(key[5], key[7], true);
    cexd(key[0], key[1], true); cexd(key[2], key[3], true);
    cexd(key[4], key[5], true); cexd(key[6], key[7], true);
}

// ---------------- S1: sort each 2048-chunk ascending ----------------
__global__ __launch_bounds__(256) void sort1_kernel(const float* __restrict__ conf,
                                                    u64* __restrict__ runs) {
    __shared__ u64 mb[2048];   // 16 KiB SoA mailbox
    int blk = blockIdx.x;
    int b = blk >> 2, c = blk & 3;
    int t = threadIdx.x;
    int base = t * EPT;               // local 0..2047
    int gbase = c * 2048 + base;      // candidate index in batch
    const float* cp = conf + b * NCAND;

    u64 key[EPT];
    if (gbase + EPT <= NCAND) {
        const float4* cp4 = (const float4*)(cp + gbase);
        float4 c0 = cp4[0], c1 = cp4[1];
        float cf[EPT] = {c0.x, c0.y, c0.z, c0.w, c1.x, c1.y, c1.z, c1.w};
#pragma unroll
        for (int e = 0; e < EPT; ++e) {
            unsigned bits = __float_as_uint(cf[e]) | 0x80000000u;
            key[e] = ((u64)(~bits) << 32) | (unsigned)(gbase + e);
        }
    } else {
#pragma unroll
        for (int e = 0; e < EPT; ++e) {
            int idx = gbase + e;
            if (idx < NCAND) {
                unsigned bits = __float_as_uint(cp[idx]) | 0x80000000u;
                key[e] = ((u64)(~bits) << 32) | (unsigned)idx;
            } else key[e] = ~0ull;   // pad sorts last
        }
    }

    cexd(key[0], key[1], true); cexd(key[2], key[3], false);
    cexd(key[4], key[5], true); cexd(key[6], key[7], false);

    cexd(key[0], key[2], true);  cexd(key[1], key[3], true);
    cexd(key[4], key[6], false); cexd(key[5], key[7], false);
    cexd(key[0], key[1], true);  cexd(key[2], key[3], true);
    cexd(key[4], key[5], false); cexd(key[6], key[7], false);

    bool up8 = ((t & 1) == 0);
    cexd(key[0], key[4], up8); cexd(key[1], key[5], up8);
    cexd(key[2], key[6], up8); cexd(key[3], key[7], up8);
    cexd(key[0], key[2], up8); cexd(key[1], key[3], up8);
    cexd(key[4], key[6], up8); cexd(key[5], key[7], up8);
    cexd(key[0], key[1], up8); cexd(key[2], key[3], up8);
    cexd(key[4], key[5], up8); cexd(key[6], key[7], up8);

    for (unsigned k = 16; k <= 2048; k <<= 1) {
        bool up = (((unsigned)base & k) == 0);
        for (unsigned j = k >> 1; j >= 8; j >>= 1) {
            unsigned m = j >> 3;
            bool kmin = (up == ((t & m) == 0));
            if (m >= 64) {
                __syncthreads();
#pragma unroll
                for (int e = 0; e < EPT; ++e) mb[e * 256 + t] = key[e];
                __syncthreads();
                int pt = t ^ (int)m;
#pragma unroll
                for (int e = 0; e < EPT; ++e) key[e] = sel(key[e], mb[e * 256 + pt], kmin);
            } else {
#pragma unroll
                for (int e = 0; e < EPT; ++e) {
                    u64 o = __shfl_xor(key[e], (int)m);
                    key[e] = sel(key[e], o, kmin);
                }
            }
        }
        cexd(key[0], key[4], up); cexd(key[1], key[5], up);
        cexd(key[2], key[6], up); cexd(key[3], key[7], up);
        cexd(key[0], key[2], up); cexd(key[1], key[3], up);
        cexd(key[4], key[6], up); cexd(key[5], key[7], up);
        cexd(key[0], key[1], up); cexd(key[2], key[3], up);
        cexd(key[4], key[5], up); cexd(key[6], key[7], up);
    }

    u64* R = runs + ((size_t)b * 4 + c) * 2048;
#pragma unroll
    for (int e = 0; e < EPT; ++e) R[base + e] = key[e];
}

// ---------------- S2: merge+prune two 2048-runs -> sorted 2048 -------
__global__ __launch_bounds__(256) void sort2_kernel(const u64* __restrict__ runs,
                                                    u64* __restrict__ half) {
    __shared__ u64 mb[2048];
    int blk = blockIdx.x;
    int b = blk >> 1, p = blk & 1;
    int t = threadIdx.x;
    int base = t * EPT;
    const u64* Av = runs + ((size_t)b * 4 + p * 2) * 2048;
    const u64* Bv = Av + 2048;

    u64 key[EPT];
#pragma unroll
    for (int e = 0; e < EPT; ++e) {
        u64 a = Av[base + e];
        u64 o = Bv[2047 - (base + e)];
        key[e] = a < o ? a : o;
    }
    bitonic_merge_2048(key, mb, t);
    u64* H = half + ((size_t)b * 2 + p) * 2048;
#pragma unroll
    for (int e = 0; e < EPT; ++e) H[base + e] = key[e];
}

// ---------------- S3: final merge+prune -> topf + fused geometry ---------
__global__ __launch_bounds__(256) void sort3_kernel(const u64* __restrict__ half,
                                                    const float* __restrict__ out,
                                                    float* __restrict__ topf,
                                                    float* __restrict__ gx1,
                                                    float* __restrict__ gy1,
                                                    float* __restrict__ gx2,
                                                    float* __restrict__ gy2,
                                                    float* __restrict__ gar,
                                                    uint32* __restrict__ gcv,
                                                    uint32* __restrict__ vwords) {
    __shared__ u64 mb[2048];
    __shared__ uint32 vb[256];
    int b = blockIdx.x;
    int t = threadIdx.x;
    int base = t * EPT;
    const u64* Av = half + (size_t)b * 2 * 2048;
    const u64* Bv = Av + 2048;

    u64 key[EPT];
#pragma unroll
    for (int e = 0; e < EPT; ++e) {
        u64 a = Av[base + e];
        u64 o = Bv[2047 - (base + e)];
        key[e] = a < o ? a : o;
    }
    bitonic_merge_2048(key, mb, t);

    const float* ob = out + (size_t)b * NCAND * CATTR;
    uint32 vbits = 0;
#pragma unroll
    for (int e = 0; e < EPT; ++e) {
        uint32 idx = (uint32)(key[e] & 0xFFFFFFFFu);
        int tg = b * TOPK + base + e;
        topf[tg] = (float)idx;
        const float* p = ob + (size_t)idx * CATTR;
        float cx = p[0], cy = p[1], w = p[2], h = p[3], cf = p[4];
        float hw_ = w * 0.5f, hh_ = h * 0.5f;  // w/2 exact
        float x1 = cx - hw_, y1 = cy - hh_, x2 = cx + hw_, y2 = cy + hh_;
        gx1[tg] = x1; gy1[tg] = y1; gx2[tg] = x2; gy2[tg] = y2;
        gar[tg] = ((x2 - x1) + 1.0f) * ((y2 - y1) + 1.0f);
        float best = p[5]; int bc = 0;
#pragma unroll
        for (int c = 1; c < 20; ++c) {      // first-max argmax (numpy semantics)
            float v = p[5 + c];
            if (v > best) { best = v; bc = c; }
        }
        gcv[tg] = (uint32)bc;
        vbits |= (cf >= 0.5f ? 1u : 0u) << e;
    }
    vb[t] = vbits;
    __syncthreads();
    if (t < 64) {
        uint32 w4 = vb[t * 4] | (vb[t * 4 + 1] << 8) | (vb[t * 4 + 2] << 16) | (vb[t * 4 + 3] << 24);
        vwords[b * 64 + t] = w4;
    }
}

// ---------------- NMS stage 2: suppression bitmask build ----------------
// Strict-upper-triangle only (bits j<=i left unwritten: provably never
// consumed by scan). Block = strip pair (p, 31-p) -> constant 33 rounds.
// Exact div-free IoU threshold (see R5 proof).
#define KMID (13421772.5 / 33554432.0)
__global__ __launch_bounds__(1024) void build_kernel(const float* __restrict__ gx1,
                                                     const float* __restrict__ gy1,
                                                     const float* __restrict__ gx2,
                                                     const float* __restrict__ gy2,
                                                     const float* __restrict__ gar,
                                                     const uint32* __restrict__ gcv,
                                                     uint32* __restrict__ rowmask) {
    __shared__ float4 x4s[TOPK];    // 32 KiB
    __shared__ float  ars[TOPK];    // 8 KiB
    __shared__ uint32 clss[TOPK];   // 8 KiB
    int bt   = blockIdx.y;
    int pr   = blockIdx.x;          // pair 0..15
    int tid  = threadIdx.x;
    int lane = tid & 63;
    int wvq  = tid >> 6;            // row-quad 0..15
    int base = bt * TOPK;
    u64* rm64 = (u64*)(rowmask + (size_t)base * NWORD);   // [row][32] u64

    for (int j = tid; j < TOPK; j += 1024) {
        int g = base + j;
        x4s[j]  = make_float4(gx1[g], gy1[g], gx2[g], gy2[g]);
        ars[j]  = gar[g];
        clss[j] = gcv[g] & 0xffu;
    }
    __syncthreads();

#pragma unroll
    for (int s = 0; s < 2; ++s) {
        int r = s ? (31 - pr) : pr;         // strip index
        int i0 = r * 64 + wvq * 4;          // this wave's 4 rows
        float4 rq[4]; float rar4[4]; uint32 rcl4[4];
#pragma unroll
        for (int k = 0; k < 4; ++k) {
            rq[k] = x4s[i0 + k]; rar4[k] = ars[i0 + k]; rcl4[k] = clss[i0 + k];
        }
        for (int cg = r; cg < 32; ++cg) {
            int j = cg * 64 + lane;
            float4 c  = x4s[j];
            float car = ars[j];
            uint32 cc = clss[j];
            u64 bal[4];
#pragma unroll
            for (int k = 0; k < 4; ++k) {
                float ix1 = fmaxf(rq[k].x, c.x);
                float iy1 = fmaxf(rq[k].y, c.y);
                float ix2 = fminf(rq[k].z, c.z);
                float iy2 = fminf(rq[k].w, c.w);
                float iw = fmaxf((ix2 - ix1) + 1.0f, 0.0f);
                float ih = fmaxf((iy2 - iy1) + 1.0f, 0.0f);
                float inter = iw * ih;
                float denom = ((rar4[k] + car) - inter) + 1e-16f;
                bool cond = ((double)inter > KMID * (double)denom) && (cc == rcl4[k]);
                bal[k] = __ballot(cond);
            }
            u64 v = bal[0];
            if (lane == 1) v = bal[1];
            if (lane == 2) v = bal[2];
            if (lane == 3) v = bal[3];
            if (lane < 4) rm64[(size_t)(i0 + lane) * 32 + cg] = v;
        }
    }
}

// ---------------- NMS stage 3: group-batched greedy scan ----------------
// 1 block/batch, 1024 thr. Wave 0 scans; waves 1-15 stream 64 KiB chunks
// into a double-buffered LDS. Per 32-candidate group:
//   1. self words -> SGPRs via readfirstlane (broadcast LDS reads)
//   2. 32-bit keep resolve as a pure SALU chain (~5 scalar ops/bit)
//   3. masked OR of ALL 32 rows, statically unrolled (independent
//      conflict-free ds_reads, mask = sext(keep bit) in SGPR) -- off the
//      decision chain, pipelined at ds throughput.
// cur via __builtin_amdgcn_readlane(supp, g): one cross-lane op per group.
// Validity folded into supp init (supp = ~vword). Garbage bits at j<=i
// (triangle build/poison) are provably never consumed.
__global__ __launch_bounds__(1024) void scan_kernel(const uint32* __restrict__ rowmask,
                                                    const uint32* __restrict__ vwords,
                                                    float* __restrict__ keepf) {
    __shared__ uint32 buf[2][CH * NWORD];   // 2 x 64 KiB
    int bt  = blockIdx.x;
    int tid = threadIdx.x;
    int wv  = tid >> 6;
    int l   = tid & 63;
    const uint32* rm = rowmask + (size_t)bt * TOPK * NWORD;

    if (wv > 0) {
        int ctid = tid - 64;
        const uint4* src = (const uint4*)rm;
        uint4* dst = (uint4*)buf[0];
        for (int o = ctid; o < CH * NWORD / 4; o += 960) dst[o] = src[o];
    }
    uint32 supp = 0, keepw = 0;
    if (wv == 0) supp = ~vwords[bt * 64 + l];
    __syncthreads();

    for (int c = 0; c < NCHUNK; ++c) {
        if (wv > 0) {
            if (c + 1 < NCHUNK) {
                int ctid = tid - 64;
                const uint4* src = (const uint4*)(rm + (size_t)(c + 1) * CH * NWORD);
                uint4* dst = (uint4*)buf[(c + 1) & 1];
                for (int o = ctid; o < CH * NWORD / 4; o += 960) dst[o] = src[o];
            }
        } else {
            const uint32* bp = buf[c & 1];
            uint32 swv[32];
#pragma unroll
            for (int k = 0; k < 32; ++k) swv[k] = bp[k * NWORD + c * GPC];
            for (int gl = 0; gl < GPC; ++gl) {
                int g = c * GPC + gl;
                uint32 sws[32];
#pragma unroll
                for (int k = 0; k < 32; ++k) sws[k] = __builtin_amdgcn_readfirstlane(swv[k]);
                if (gl + 1 < GPC) {   // prefetch next group's self words
#pragma unroll
                    for (int k = 0; k < 32; ++k)
                        swv[k] = bp[((gl + 1) * 32 + k) * NWORD + (g + 1)];
                }
                uint32 cur = __builtin_amdgcn_readlane(supp, g);
                uint32 keep = 0;
#pragma unroll
                for (int k = 0; k < 32; ++k) {   // SALU chain: all operands uniform
                    uint32 bitk = (cur >> k) & 1u;
                    keep |= (bitk ^ 1u) << k;
                    cur |= sws[k] & (bitk - 1u); // bitk=0 (kept) -> all-ones
                }
                if (l == g) keepw = keep;
                uint32 upd = 0;
#pragma unroll
                for (int k = 0; k < 32; ++k) {   // independent, conflict-free
                    uint32 mk = (uint32)((int)(keep << (31 - k)) >> 31);
                    upd |= bp[(gl * 32 + k) * NWORD + l] & mk;
                }
                supp |= upd;
            }
        }
        __syncthreads();
    }

    if (wv == 0) {
#pragma unroll
        for (int k = 0; k < 32; ++k)
            keepf[bt * TOPK + l * 32 + k] = (float)((keepw >> k) & 1u);
    }
}

extern "C" void kernel_launch(void* const* d_in, const int* in_sizes, int n_in,
                              void* d_out, int out_size, void* d_ws, size_t ws_size,
                              hipStream_t stream) {
    const float* inp     = (const float*)d_in[0];
    const float* anchors = (const float*)d_in[1];
    float* out   = (float*)d_out;                        // [B, N, 25]
    float* topf  = out  + (size_t)B * NCAND * CATTR;     // [B, 2048] indices as float
    float* keepf = topf + (size_t)B * TOPK;              // [B, 2048] 0/1 as float

    // workspace layout
    float*  cws = (float*)d_ws;                          // [B, NCAND] conf
    float*  gx1 = cws + B * NCAND;
    float*  gy1 = gx1 + B * TOPK;
    float*  gx2 = gy1 + B * TOPK;
    float*  gy2 = gx2 + B * TOPK;
    float*  gar = gy2 + B * TOPK;
    uint32* gcv = (uint32*)(gar + B * TOPK);
    uint32* rowmask = gcv + B * TOPK;                    // 16*2048*64 u32 = 8 MiB
    uint32* vwords  = rowmask + (size_t)B * TOPK * NWORD;
    // sort scratch aliases onto rowmask (sort completes before build writes)
    u64* runs = (u64*)rowmask;                           // 1 MiB
    u64* half = runs + (size_t)B * 4 * 2048;             // 0.5 MiB

    decode_kernel<<<(B * NCAND) / 256, 256, 0, stream>>>(inp, anchors, out, cws);
    sort1_kernel<<<B * 4, 256, 0, stream>>>(cws, runs);
    sort2_kernel<<<B * 2, 256, 0, stream>>>(runs, half);
    sort3_kernel<<<B, 256, 0, stream>>>(half, out, topf, gx1, gy1, gx2, gy2, gar, gcv, vwords);
    build_kernel<<<dim3(16, B), 1024, 0, stream>>>(gx1, gy1, gx2, gy2, gar, gcv, rowmask);
    scan_kernel<<<B, 1024, 0, stream>>>(rowmask, vwords, keepf);
}

// Round 9
// 218.024 us; speedup vs baseline: 1.1803x; 1.0104x over previous
//
#include <hip/hip_runtime.h>

#pragma clang fp contract(off)

#define B 16
#define A 3
#define HGT 52
#define WID 52
#define HW 2704
#define NCAND 8112   // A*HW
#define CATTR 25
#define TOPK 2048
#define NWORD 64     // 64 u32 words x 32 bits = 2048 cols
#define CH 256       // rows per scan chunk
#define NCHUNK (TOPK / CH)   // 8
#define GPC (CH / 32)        // 8 groups per chunk
#define CHP 260      // padded chunk-row stride (words); %4==0 keeps b128 align
#define EPT 8        // sort: elements per thread

typedef unsigned int uint32;
typedef unsigned long long u64;

// ---------------- decode ----------------
// grid 507 x 256: exactly B*NCAND threads. LDS transpose so the 25-attr AoS
// output is stored as contiguous coalesced float4s.
__global__ __launch_bounds__(256) void decode_kernel(const float* __restrict__ inp,
                                                     const float* __restrict__ anchors,
                                                     float* __restrict__ out,
                                                     float* __restrict__ cws) {
    __shared__ float sm[256 * CATTR];   // 25.6 KiB, candidate-major == out order
    int tid = threadIdx.x;
    int t = blockIdx.x * 256 + tid;     // < B*NCAND (129792 = 507*256 exactly)
    int b  = t / NCAND;
    int n  = t - b * NCAND;
    int a  = n / HW;
    int hw = n - a * HW;
    int gy = hw / WID;
    int gx = hw - gy * WID;
    const float* ip = inp + ((size_t)(b * (A * CATTR) + a * CATTR)) * HW + hw;
    float* sp = sm + tid * CATTR;

    float p0 = ip[0 * HW], p1 = ip[1 * HW], p2 = ip[2 * HW], p3 = ip[3 * HW], p4 = ip[4 * HW];
    float sx = 1.0f / (1.0f + expf(-p0));
    float sy = 1.0f / (1.0f + expf(-p1));
    float bx = (sx + (float)gx) * 8.0f;   // stride = 8 exactly
    float by = (sy + (float)gy) * 8.0f;
    float bw = expf(p2) * anchors[a * 2 + 0];   // (anchor/8)*8 exact
    float bh = expf(p3) * anchors[a * 2 + 1];
    float cf = 1.0f / (1.0f + expf(-p4));
    sp[0] = bx; sp[1] = by; sp[2] = bw; sp[3] = bh; sp[4] = cf;
    cws[t] = cf;   // contiguous conf for the sort
#pragma unroll
    for (int c = 0; c < 20; ++c) {
        float v = ip[(5 + c) * HW];
        sp[5 + c] = 1.0f / (1.0f + expf(-v));
    }
    __syncthreads();
    const float4* sm4 = (const float4*)sm;
    float4* o4 = (float4*)(out + (size_t)blockIdx.x * 256 * CATTR);
#pragma unroll
    for (int k = 0; k < 6; ++k) o4[k * 256 + tid] = sm4[k * 256 + tid];
    if (tid < 64) o4[1536 + tid] = sm4[1536 + tid];
}

// ---------------- sort helpers ----------------
// key = (~(conf_bits|sign) << 32) | idx ; ascending == conf desc, idx asc.
__device__ __forceinline__ void cexd(u64& a, u64& b, bool up) {
    if ((a > b) == up) { u64 tmp = a; a = b; b = tmp; }
}

__device__ __forceinline__ u64 sel(u64 k, u64 o, bool kmin) {
    return kmin ? (k < o ? k : o) : (k > o ? k : o);
}

// bitonic merge of a 2048-element bitonic sequence to ascending order.
__device__ __forceinline__ void bitonic_merge_2048(u64 key[EPT], u64* mb, int t) {
    for (unsigned j = 1024; j >= 8; j >>= 1) {
        unsigned m = j >> 3;
        bool kmin = ((t & m) == 0);
        if (m >= 64) {
            __syncthreads();
#pragma unroll
            for (int e = 0; e < EPT; ++e) mb[e * 256 + t] = key[e];
            __syncthreads();
            int pt = t ^ (int)m;
#pragma unroll
            for (int e = 0; e < EPT; ++e) key[e] = sel(key[e], mb[e * 256 + pt], kmin);
        } else {
#pragma unroll
            for (int e = 0; e < EPT; ++e) {
                u64 o = __shfl_xor(key[e], (int)m);
                key[e] = sel(key[e], o, kmin);
            }
        }
    }
    cexd(key[0], key[4], true); cexd(key[1], key[5], true);
    cexd(key[2], key[6], true); cexd(key[3], key[7], true);
    cexd(key[0], key[2], true); cexd(key[1], key[3], true);
    cexd(key[4], key[6], true); cexd(key[5], key[7], true);
    cexd(key[0], key[1], true); cexd(key[2], key[3], true);
    cexd(key[4], key[5], true); cexd(key[6], key[7], true);
}

// ---------------- S1: sort each 2048-chunk ascending ----------------
__global__ __launch_bounds__(256) void sort1_kernel(const float* __restrict__ conf,
                                                    u64* __restrict__ runs) {
    __shared__ u64 mb[2048];   // 16 KiB SoA mailbox
    int blk = blockIdx.x;
    int b = blk >> 2, c = blk & 3;
    int t = threadIdx.x;
    int base = t * EPT;               // local 0..2047
    int gbase = c * 2048 + base;      // candidate index in batch
    const float* cp = conf + b * NCAND;

    u64 key[EPT];
    if (gbase + EPT <= NCAND) {
        const float4* cp4 = (const float4*)(cp + gbase);
        float4 c0 = cp4[0], c1 = cp4[1];
        float cf[EPT] = {c0.x, c0.y, c0.z, c0.w, c1.x, c1.y, c1.z, c1.w};
#pragma unroll
        for (int e = 0; e < EPT; ++e) {
            unsigned bits = __float_as_uint(cf[e]) | 0x80000000u;
            key[e] = ((u64)(~bits) << 32) | (unsigned)(gbase + e);
        }
    } else {
#pragma unroll
        for (int e = 0; e < EPT; ++e) {
            int idx = gbase + e;
            if (idx < NCAND) {
                unsigned bits = __float_as_uint(cp[idx]) | 0x80000000u;
                key[e] = ((u64)(~bits) << 32) | (unsigned)idx;
            } else key[e] = ~0ull;   // pad sorts last
        }
    }

    cexd(key[0], key[1], true); cexd(key[2], key[3], false);
    cexd(key[4], key[5], true); cexd(key[6], key[7], false);

    cexd(key[0], key[2], true);  cexd(key[1], key[3], true);
    cexd(key[4], key[6], false); cexd(key[5], key[7], false);
    cexd(key[0], key[1], true);  cexd(key[2], key[3], true);
    cexd(key[4], key[5], false); cexd(key[6], key[7], false);

    bool up8 = ((t & 1) == 0);
    cexd(key[0], key[4], up8); cexd(key[1], key[5], up8);
    cexd(key[2], key[6], up8); cexd(key[3], key[7], up8);
    cexd(key[0], key[2], up8); cexd(key[1], key[3], up8);
    cexd(key[4], key[6], up8); cexd(key[5], key[7], up8);
    cexd(key[0], key[1], up8); cexd(key[2], key[3], up8);
    cexd(key[4], key[5], up8); cexd(key[6], key[7], up8);

    for (unsigned k = 16; k <= 2048; k <<= 1) {
        bool up = (((unsigned)base & k) == 0);
        for (unsigned j = k >> 1; j >= 8; j >>= 1) {
            unsigned m = j >> 3;
            bool kmin = (up == ((t & m) == 0));
            if (m >= 64) {
                __syncthreads();
#pragma unroll
                for (int e = 0; e < EPT; ++e) mb[e * 256 + t] = key[e];
                __syncthreads();
                int pt = t ^ (int)m;
#pragma unroll
                for (int e = 0; e < EPT; ++e) key[e] = sel(key[e], mb[e * 256 + pt], kmin);
            } else {
#pragma unroll
                for (int e = 0; e < EPT; ++e) {
                    u64 o = __shfl_xor(key[e], (int)m);
                    key[e] = sel(key[e], o, kmin);
                }
            }
        }
        cexd(key[0], key[4], up); cexd(key[1], key[5], up);
        cexd(key[2], key[6], up); cexd(key[3], key[7], up);
        cexd(key[0], key[2], up); cexd(key[1], key[3], up);
        cexd(key[4], key[6], up); cexd(key[5], key[7], up);
        cexd(key[0], key[1], up); cexd(key[2], key[3], up);
        cexd(key[4], key[5], up); cexd(key[6], key[7], up);
    }

    u64* R = runs + ((size_t)b * 4 + c) * 2048;
#pragma unroll
    for (int e = 0; e < EPT; ++e) R[base + e] = key[e];
}

// ---------------- S2: merge+prune two 2048-runs -> sorted 2048 -------
__global__ __launch_bounds__(256) void sort2_kernel(const u64* __restrict__ runs,
                                                    u64* __restrict__ half) {
    __shared__ u64 mb[2048];
    int blk = blockIdx.x;
    int b = blk >> 1, p = blk & 1;
    int t = threadIdx.x;
    int base = t * EPT;
    const u64* Av = runs + ((size_t)b * 4 + p * 2) * 2048;
    const u64* Bv = Av + 2048;

    u64 key[EPT];
#pragma unroll
    for (int e = 0; e < EPT; ++e) {
        u64 a = Av[base + e];
        u64 o = Bv[2047 - (base + e)];
        key[e] = a < o ? a : o;
    }
    bitonic_merge_2048(key, mb, t);
    u64* H = half + ((size_t)b * 2 + p) * 2048;
#pragma unroll
    for (int e = 0; e < EPT; ++e) H[base + e] = key[e];
}

// ---------------- S3: final merge+prune -> topf + fused geometry ---------
__global__ __launch_bounds__(256) void sort3_kernel(const u64* __restrict__ half,
                                                    const float* __restrict__ out,
                                                    float* __restrict__ topf,
                                                    float* __restrict__ gx1,
                                                    float* __restrict__ gy1,
                                                    float* __restrict__ gx2,
                                                    float* __restrict__ gy2,
                                                    float* __restrict__ gar,
                                                    uint32* __restrict__ gcv,
                                                    uint32* __restrict__ vwords) {
    __shared__ u64 mb[2048];
    __shared__ uint32 vb[256];
    int b = blockIdx.x;
    int t = threadIdx.x;
    int base = t * EPT;
    const u64* Av = half + (size_t)b * 2 * 2048;
    const u64* Bv = Av + 2048;

    u64 key[EPT];
#pragma unroll
    for (int e = 0; e < EPT; ++e) {
        u64 a = Av[base + e];
        u64 o = Bv[2047 - (base + e)];
        key[e] = a < o ? a : o;
    }
    bitonic_merge_2048(key, mb, t);

    const float* ob = out + (size_t)b * NCAND * CATTR;
    uint32 vbits = 0;
#pragma unroll
    for (int e = 0; e < EPT; ++e) {
        uint32 idx = (uint32)(key[e] & 0xFFFFFFFFu);
        int tg = b * TOPK + base + e;
        topf[tg] = (float)idx;
        const float* p = ob + (size_t)idx * CATTR;
        float cx = p[0], cy = p[1], w = p[2], h = p[3], cf = p[4];
        float hw_ = w * 0.5f, hh_ = h * 0.5f;  // w/2 exact
        float x1 = cx - hw_, y1 = cy - hh_, x2 = cx + hw_, y2 = cy + hh_;
        gx1[tg] = x1; gy1[tg] = y1; gx2[tg] = x2; gy2[tg] = y2;
        gar[tg] = ((x2 - x1) + 1.0f) * ((y2 - y1) + 1.0f);
        float best = p[5]; int bc = 0;
#pragma unroll
        for (int c = 1; c < 20; ++c) {      // first-max argmax (numpy semantics)
            float v = p[5 + c];
            if (v > best) { best = v; bc = c; }
        }
        gcv[tg] = (uint32)bc;
        vbits |= (cf >= 0.5f ? 1u : 0u) << e;
    }
    vb[t] = vbits;
    __syncthreads();
    if (t < 64) {
        uint32 w4 = vb[t * 4] | (vb[t * 4 + 1] << 8) | (vb[t * 4 + 2] << 16) | (vb[t * 4 + 3] << 24);
        vwords[b * 64 + t] = w4;
    }
}

// ---------------- NMS stage 2: suppression bitmask build ----------------
// Strict-upper-triangle only (bits j<=i left unwritten: provably never
// consumed by scan). Block = strip pair (p, 31-p) -> constant 33 rounds.
// Exact div-free IoU threshold (see R5 proof).
#define KMID (13421772.5 / 33554432.0)
__global__ __launch_bounds__(1024) void build_kernel(const float* __restrict__ gx1,
                                                     const float* __restrict__ gy1,
                                                     const float* __restrict__ gx2,
                                                     const float* __restrict__ gy2,
                                                     const float* __restrict__ gar,
                                                     const uint32* __restrict__ gcv,
                                                     uint32* __restrict__ rowmask) {
    __shared__ float4 x4s[TOPK];    // 32 KiB
    __shared__ float  ars[TOPK];    // 8 KiB
    __shared__ uint32 clss[TOPK];   // 8 KiB
    int bt   = blockIdx.y;
    int pr   = blockIdx.x;          // pair 0..15
    int tid  = threadIdx.x;
    int lane = tid & 63;
    int wvq  = tid >> 6;            // row-quad 0..15
    int base = bt * TOPK;
    u64* rm64 = (u64*)(rowmask + (size_t)base * NWORD);   // [row][32] u64

    for (int j = tid; j < TOPK; j += 1024) {
        int g = base + j;
        x4s[j]  = make_float4(gx1[g], gy1[g], gx2[g], gy2[g]);
        ars[j]  = gar[g];
        clss[j] = gcv[g] & 0xffu;
    }
    __syncthreads();

#pragma unroll
    for (int s = 0; s < 2; ++s) {
        int r = s ? (31 - pr) : pr;         // strip index
        int i0 = r * 64 + wvq * 4;          // this wave's 4 rows
        float4 rq[4]; float rar4[4]; uint32 rcl4[4];
#pragma unroll
        for (int k = 0; k < 4; ++k) {
            rq[k] = x4s[i0 + k]; rar4[k] = ars[i0 + k]; rcl4[k] = clss[i0 + k];
        }
        for (int cg = r; cg < 32; ++cg) {
            int j = cg * 64 + lane;
            float4 c  = x4s[j];
            float car = ars[j];
            uint32 cc = clss[j];
            u64 bal[4];
#pragma unroll
            for (int k = 0; k < 4; ++k) {
                float ix1 = fmaxf(rq[k].x, c.x);
                float iy1 = fmaxf(rq[k].y, c.y);
                float ix2 = fminf(rq[k].z, c.z);
                float iy2 = fminf(rq[k].w, c.w);
                float iw = fmaxf((ix2 - ix1) + 1.0f, 0.0f);
                float ih = fmaxf((iy2 - iy1) + 1.0f, 0.0f);
                float inter = iw * ih;
                float denom = ((rar4[k] + car) - inter) + 1e-16f;
                bool cond = ((double)inter > KMID * (double)denom) && (cc == rcl4[k]);
                bal[k] = __ballot(cond);
            }
            u64 v = bal[0];
            if (lane == 1) v = bal[1];
            if (lane == 2) v = bal[2];
            if (lane == 3) v = bal[3];
            if (lane < 4) rm64[(size_t)(i0 + lane) * 32 + cg] = v;
        }
    }
}

// ---------------- NMS stage 3: group-batched greedy scan ----------------
// 1 block/batch, 1024 thr. Wave 0 scans; waves 1-15 stream chunks into a
// double-buffered TRANSPOSED LDS layout buf[w*CHP + r] (CHP=260 pad):
//   - masked-OR: lane l = word l -> 8x ds_read_b128 (stride 260 words
//     between lanes = uniform 8 accesses/bank = b128 inherent floor)
//   - self words of group g: word g, rows gl*32..+31 -> contiguous ->
//     8x broadcast ds_read_b128 (uniform address)
// Copy waves scrub self-word strict-upper garbage (bits <= row%32 of word
// row/32), making cur monotone -> keep = ~cur_final (3-op resolve step).
// Issue order per group: rw loads -> readlane -> resolve(sw, landed last
// iter) -> prefetch sw(g+1) -> masked-OR (rw landed under resolve).
// Garbage at j<=i elsewhere provably never consumed (R5/R6 proof).
__global__ __launch_bounds__(1024) void scan_kernel(const uint32* __restrict__ rowmask,
                                                    const uint32* __restrict__ vwords,
                                                    float* __restrict__ keepf) {
    __shared__ uint32 buf[2][64 * CHP];   // 2 x 66,560 B
    int bt  = blockIdx.x;
    int tid = threadIdx.x;
    int wv  = tid >> 6;
    int l   = tid & 63;
    const uint32* rm = rowmask + (size_t)bt * TOPK * NWORD;

    uint32 supp = 0, keepw = 0;
    if (wv == 0) supp = ~vwords[bt * 64 + l];

    // chunk 0 copy
    if (wv > 0) {
        int ctid = tid - 64;
        uint32* dst = buf[0];
        for (int o = ctid; o < 4096; o += 960) {
            int q = o >> 8, r = o & 255;
            uint4 v = *(const uint4*)(rm + (size_t)r * NWORD + q * 4);
            int sg = r >> 5;                       // chunk 0: global row == r
            uint32 smsk = ~((2u << (r & 31)) - 1u);
            uint32 vv[4] = {v.x, v.y, v.z, v.w};
#pragma unroll
            for (int j = 0; j < 4; ++j) {
                int w = 4 * q + j;
                uint32 x = vv[j];
                if (w == sg) x &= smsk;
                dst[w * CHP + r] = x;
            }
        }
    }
    __syncthreads();

    for (int c = 0; c < NCHUNK; ++c) {
        if (wv > 0) {
            if (c + 1 < NCHUNK) {
                int ctid = tid - 64;
                const uint32* src = rm + (size_t)(c + 1) * CH * NWORD;
                uint32* dst = buf[(c + 1) & 1];
                for (int o = ctid; o < 4096; o += 960) {
                    int q = o >> 8, r = o & 255;
                    uint4 v = *(const uint4*)(src + (size_t)r * NWORD + q * 4);
                    int gi = (c + 1) * CH + r;
                    int sg = gi >> 5;
                    uint32 smsk = ~((2u << (gi & 31)) - 1u);
                    uint32 vv[4] = {v.x, v.y, v.z, v.w};
#pragma unroll
                    for (int j = 0; j < 4; ++j) {
                        int w = 4 * q + j;
                        uint32 x = vv[j];
                        if (w == sg) x &= smsk;
                        dst[w * CHP + r] = x;
                    }
                }
            }
        } else {
            const uint32* bp = buf[c & 1];
            // self words for first group of chunk
            uint4 sq[8];
            {
                int g0 = c * GPC;
                const uint4* sp = (const uint4*)(bp + g0 * CHP);   // rows 0..31
#pragma unroll
                for (int q = 0; q < 8; ++q) sq[q] = sp[q];
            }
            for (int gl = 0; gl < GPC; ++gl) {
                int g = c * GPC + gl;
                // 1. issue masked-OR row loads (independent of resolve)
                uint4 rwq[8];
                const uint4* rp = (const uint4*)(bp + l * CHP + gl * 32);
#pragma unroll
                for (int q = 0; q < 8; ++q) rwq[q] = rp[q];
                // 2. snapshot current supp word
                uint32 cur = __builtin_amdgcn_readlane(supp, g);
                // 3. resolve: monotone chain (self words scrubbed in copy)
#pragma unroll
                for (int q = 0; q < 8; ++q) {
                    uint32 s0 = sq[q].x, s1 = sq[q].y, s2 = sq[q].z, s3 = sq[q].w;
                    int k = q * 4;
                    cur |= s0 & ((((cur >> (k + 0)) & 1u)) - 1u);
                    cur |= s1 & ((((cur >> (k + 1)) & 1u)) - 1u);
                    cur |= s2 & ((((cur >> (k + 2)) & 1u)) - 1u);
                    cur |= s3 & ((((cur >> (k + 3)) & 1u)) - 1u);
                }
                uint32 keep = ~cur;
                if (l == g) keepw = keep;
                // 4. prefetch next group's self words (overwrites sq)
                if (gl + 1 < GPC) {
                    const uint4* sp = (const uint4*)(bp + (g + 1) * CHP + (gl + 1) * 32);
#pragma unroll
                    for (int q = 0; q < 8; ++q) sq[q] = sp[q];
                }
                // 5. masked OR of all 32 rows into supp
                uint32 upd = 0;
#pragma unroll
                for (int q = 0; q < 8; ++q) {
                    int k = q * 4;
                    upd |= rwq[q].x & (uint32)(((int)(keep << (31 - (k + 0)))) >> 31);
                    upd |= rwq[q].y & (uint32)(((int)(keep << (31 - (k + 1)))) >> 31);
                    upd |= rwq[q].z & (uint32)(((int)(keep << (31 - (k + 2)))) >> 31);
                    upd |= rwq[q].w & (uint32)(((int)(keep << (31 - (k + 3)))) >> 31);
                }
                supp |= upd;
            }
        }
        __syncthreads();
    }

    if (wv == 0) {
#pragma unroll
        for (int k = 0; k < 32; ++k)
            keepf[bt * TOPK + l * 32 + k] = (float)((keepw >> k) & 1u);
    }
}

extern "C" void kernel_launch(void* const* d_in, const int* in_sizes, int n_in,
                              void* d_out, int out_size, void* d_ws, size_t ws_size,
                              hipStream_t stream) {
    const float* inp     = (const float*)d_in[0];
    const float* anchors = (const float*)d_in[1];
    float* out   = (float*)d_out;                        // [B, N, 25]
    float* topf  = out  + (size_t)B * NCAND * CATTR;     // [B, 2048] indices as float
    float* keepf = topf + (size_t)B * TOPK;              // [B, 2048] 0/1 as float

    // workspace layout
    float*  cws = (float*)d_ws;                          // [B, NCAND] conf
    float*  gx1 = cws + B * NCAND;
    float*  gy1 = gx1 + B * TOPK;
    float*  gx2 = gy1 + B * TOPK;
    float*  gy2 = gx2 + B * TOPK;
    float*  gar = gy2 + B * TOPK;
    uint32* gcv = (uint32*)(gar + B * TOPK);
    uint32* rowmask = gcv + B * TOPK;                    // 16*2048*64 u32 = 8 MiB
    uint32* vwords  = rowmask + (size_t)B * TOPK * NWORD;
    // sort scratch aliases onto rowmask (sort completes before build writes)
    u64* runs = (u64*)rowmask;                           // 1 MiB
    u64* half = runs + (size_t)B * 4 * 2048;             // 0.5 MiB

    decode_kernel<<<(B * NCAND) / 256, 256, 0, stream>>>(inp, anchors, out, cws);
    sort1_kernel<<<B * 4, 256, 0, stream>>>(cws, runs);
    sort2_kernel<<<B * 2, 256, 0, stream>>>(runs, half);
    sort3_kernel<<<B, 256, 0, stream>>>(half, out, topf, gx1, gy1, gx2, gy2, gar, gcv, vwords);
    build_kernel<<<dim3(16, B), 1024, 0, stream>>>(gx1, gy1, gx2, gy2, gar, gcv, rowmask);
    scan_kernel<<<B, 1024, 0, stream>>>(rowmask, vwords, keepf);
}

// Round 10
// 196.585 us; speedup vs baseline: 1.3090x; 1.1091x over previous
//
#include <hip/hip_runtime.h>

#pragma clang fp contract(off)

#define B 16
#define A 3
#define HGT 52
#define WID 52
#define HW 2704
#define NCAND 8112   // A*HW
#define CATTR 25
#define TOPK 2048
#define NWORD 64     // 64 u32 words x 32 bits = 2048 cols
#define CH 256       // rows per scan chunk
#define NCHUNK (TOPK / CH)   // 8
#define GPC (CH / 32)        // 8 groups per chunk
#define CHP 260      // padded chunk-row stride (words); %4==0 keeps b128 align
#define EPT 8        // sort: elements per thread

typedef unsigned int uint32;
typedef unsigned long long u64;

// ---------------- decode ----------------
__global__ __launch_bounds__(256) void decode_kernel(const float* __restrict__ inp,
                                                     const float* __restrict__ anchors,
                                                     float* __restrict__ out,
                                                     float* __restrict__ cws) {
    __shared__ float sm[256 * CATTR];   // 25.6 KiB, candidate-major == out order
    int tid = threadIdx.x;
    int t = blockIdx.x * 256 + tid;     // < B*NCAND (129792 = 507*256 exactly)
    int b  = t / NCAND;
    int n  = t - b * NCAND;
    int a  = n / HW;
    int hw = n - a * HW;
    int gy = hw / WID;
    int gx = hw - gy * WID;
    const float* ip = inp + ((size_t)(b * (A * CATTR) + a * CATTR)) * HW + hw;
    float* sp = sm + tid * CATTR;

    float p0 = ip[0 * HW], p1 = ip[1 * HW], p2 = ip[2 * HW], p3 = ip[3 * HW], p4 = ip[4 * HW];
    float sx = 1.0f / (1.0f + expf(-p0));
    float sy = 1.0f / (1.0f + expf(-p1));
    float bx = (sx + (float)gx) * 8.0f;   // stride = 8 exactly
    float by = (sy + (float)gy) * 8.0f;
    float bw = expf(p2) * anchors[a * 2 + 0];   // (anchor/8)*8 exact
    float bh = expf(p3) * anchors[a * 2 + 1];
    float cf = 1.0f / (1.0f + expf(-p4));
    sp[0] = bx; sp[1] = by; sp[2] = bw; sp[3] = bh; sp[4] = cf;
    cws[t] = cf;   // contiguous conf for the sort
#pragma unroll
    for (int c = 0; c < 20; ++c) {
        float v = ip[(5 + c) * HW];
        sp[5 + c] = 1.0f / (1.0f + expf(-v));
    }
    __syncthreads();
    const float4* sm4 = (const float4*)sm;
    float4* o4 = (float4*)(out + (size_t)blockIdx.x * 256 * CATTR);
#pragma unroll
    for (int k = 0; k < 6; ++k) o4[k * 256 + tid] = sm4[k * 256 + tid];
    if (tid < 64) o4[1536 + tid] = sm4[1536 + tid];
}

// ---------------- sort helpers ----------------
// key = (~(conf_bits|sign) << 32) | idx ; ascending == conf desc, idx asc.
__device__ __forceinline__ void cexd(u64& a, u64& b, bool up) {
    if ((a > b) == up) { u64 tmp = a; a = b; b = tmp; }
}

__device__ __forceinline__ u64 sel(u64 k, u64 o, bool kmin) {
    return kmin ? (k < o ? k : o) : (k > o ? k : o);
}

// bitonic merge of a 2048-element bitonic sequence to ascending order.
__device__ __forceinline__ void bitonic_merge_2048(u64 key[EPT], u64* mb, int t) {
    for (unsigned j = 1024; j >= 8; j >>= 1) {
        unsigned m = j >> 3;
        bool kmin = ((t & m) == 0);
        if (m >= 64) {
            __syncthreads();
#pragma unroll
            for (int e = 0; e < EPT; ++e) mb[e * 256 + t] = key[e];
            __syncthreads();
            int pt = t ^ (int)m;
#pragma unroll
            for (int e = 0; e < EPT; ++e) key[e] = sel(key[e], mb[e * 256 + pt], kmin);
        } else {
#pragma unroll
            for (int e = 0; e < EPT; ++e) {
                u64 o = __shfl_xor(key[e], (int)m);
                key[e] = sel(key[e], o, kmin);
            }
        }
    }
    cexd(key[0], key[4], true); cexd(key[1], key[5], true);
    cexd(key[2], key[6], true); cexd(key[3], key[7], true);
    cexd(key[0], key[2], true); cexd(key[1], key[3], true);
    cexd(key[4], key[6], true); cexd(key[5], key[7], true);
    cexd(key[0], key[1], true); cexd(key[2], key[3], true);
    cexd(key[4], key[5], true); cexd(key[6], key[7], true);
}

// ---------------- S1: sort each 2048-chunk ascending ----------------
__global__ __launch_bounds__(256) void sort1_kernel(const float* __restrict__ conf,
                                                    u64* __restrict__ runs) {
    __shared__ u64 mb[2048];   // 16 KiB SoA mailbox
    int blk = blockIdx.x;
    int b = blk >> 2, c = blk & 3;
    int t = threadIdx.x;
    int base = t * EPT;               // local 0..2047
    int gbase = c * 2048 + base;      // candidate index in batch
    const float* cp = conf + b * NCAND;

    u64 key[EPT];
    if (gbase + EPT <= NCAND) {
        const float4* cp4 = (const float4*)(cp + gbase);
        float4 c0 = cp4[0], c1 = cp4[1];
        float cf[EPT] = {c0.x, c0.y, c0.z, c0.w, c1.x, c1.y, c1.z, c1.w};
#pragma unroll
        for (int e = 0; e < EPT; ++e) {
            unsigned bits = __float_as_uint(cf[e]) | 0x80000000u;
            key[e] = ((u64)(~bits) << 32) | (unsigned)(gbase + e);
        }
    } else {
#pragma unroll
        for (int e = 0; e < EPT; ++e) {
            int idx = gbase + e;
            if (idx < NCAND) {
                unsigned bits = __float_as_uint(cp[idx]) | 0x80000000u;
                key[e] = ((u64)(~bits) << 32) | (unsigned)idx;
            } else key[e] = ~0ull;   // pad sorts last
        }
    }

    cexd(key[0], key[1], true); cexd(key[2], key[3], false);
    cexd(key[4], key[5], true); cexd(key[6], key[7], false);

    cexd(key[0], key[2], true);  cexd(key[1], key[3], true);
    cexd(key[4], key[6], false); cexd(key[5], key[7], false);
    cexd(key[0], key[1], true);  cexd(key[2], key[3], true);
    cexd(key[4], key[5], false); cexd(key[6], key[7], false);

    bool up8 = ((t & 1) == 0);
    cexd(key[0], key[4], up8); cexd(key[1], key[5], up8);
    cexd(key[2], key[6], up8); cexd(key[3], key[7], up8);
    cexd(key[0], key[2], up8); cexd(key[1], key[3], up8);
    cexd(key[4], key[6], up8); cexd(key[5], key[7], up8);
    cexd(key[0], key[1], up8); cexd(key[2], key[3], up8);
    cexd(key[4], key[5], up8); cexd(key[6], key[7], up8);

    for (unsigned k = 16; k <= 2048; k <<= 1) {
        bool up = (((unsigned)base & k) == 0);
        for (unsigned j = k >> 1; j >= 8; j >>= 1) {
            unsigned m = j >> 3;
            bool kmin = (up == ((t & m) == 0));
            if (m >= 64) {
                __syncthreads();
#pragma unroll
                for (int e = 0; e < EPT; ++e) mb[e * 256 + t] = key[e];
                __syncthreads();
                int pt = t ^ (int)m;
#pragma unroll
                for (int e = 0; e < EPT; ++e) key[e] = sel(key[e], mb[e * 256 + pt], kmin);
            } else {
#pragma unroll
                for (int e = 0; e < EPT; ++e) {
                    u64 o = __shfl_xor(key[e], (int)m);
                    key[e] = sel(key[e], o, kmin);
                }
            }
        }
        cexd(key[0], key[4], up); cexd(key[1], key[5], up);
        cexd(key[2], key[6], up); cexd(key[3], key[7], up);
        cexd(key[0], key[2], up); cexd(key[1], key[3], up);
        cexd(key[4], key[6], up); cexd(key[5], key[7], up);
        cexd(key[0], key[1], up); cexd(key[2], key[3], up);
        cexd(key[4], key[5], up); cexd(key[6], key[7], up);
    }

    u64* R = runs + ((size_t)b * 4 + c) * 2048;
#pragma unroll
    for (int e = 0; e < EPT; ++e) R[base + e] = key[e];
}

// ---------------- S2: merge+prune two 2048-runs -> sorted 2048 -------
__global__ __launch_bounds__(256) void sort2_kernel(const u64* __restrict__ runs,
                                                    u64* __restrict__ half) {
    __shared__ u64 mb[2048];
    int blk = blockIdx.x;
    int b = blk >> 1, p = blk & 1;
    int t = threadIdx.x;
    int base = t * EPT;
    const u64* Av = runs + ((size_t)b * 4 + p * 2) * 2048;
    const u64* Bv = Av + 2048;

    u64 key[EPT];
#pragma unroll
    for (int e = 0; e < EPT; ++e) {
        u64 a = Av[base + e];
        u64 o = Bv[2047 - (base + e)];
        key[e] = a < o ? a : o;
    }
    bitonic_merge_2048(key, mb, t);
    u64* H = half + ((size_t)b * 2 + p) * 2048;
#pragma unroll
    for (int e = 0; e < EPT; ++e) H[base + e] = key[e];
}

// ---------------- S3: final merge+prune -> topf + fused geometry ---------
__global__ __launch_bounds__(256) void sort3_kernel(const u64* __restrict__ half,
                                                    const float* __restrict__ out,
                                                    float* __restrict__ topf,
                                                    float* __restrict__ gx1,
                                                    float* __restrict__ gy1,
                                                    float* __restrict__ gx2,
                                                    float* __restrict__ gy2,
                                                    float* __restrict__ gar,
                                                    uint32* __restrict__ gcv,
                                                    uint32* __restrict__ vwords) {
    __shared__ u64 mb[2048];
    __shared__ uint32 vb[256];
    int b = blockIdx.x;
    int t = threadIdx.x;
    int base = t * EPT;
    const u64* Av = half + (size_t)b * 2 * 2048;
    const u64* Bv = Av + 2048;

    u64 key[EPT];
#pragma unroll
    for (int e = 0; e < EPT; ++e) {
        u64 a = Av[base + e];
        u64 o = Bv[2047 - (base + e)];
        key[e] = a < o ? a : o;
    }
    bitonic_merge_2048(key, mb, t);

    const float* ob = out + (size_t)b * NCAND * CATTR;
    uint32 vbits = 0;
#pragma unroll
    for (int e = 0; e < EPT; ++e) {
        uint32 idx = (uint32)(key[e] & 0xFFFFFFFFu);
        int tg = b * TOPK + base + e;
        topf[tg] = (float)idx;
        const float* p = ob + (size_t)idx * CATTR;
        float cx = p[0], cy = p[1], w = p[2], h = p[3], cf = p[4];
        float hw_ = w * 0.5f, hh_ = h * 0.5f;  // w/2 exact
        float x1 = cx - hw_, y1 = cy - hh_, x2 = cx + hw_, y2 = cy + hh_;
        gx1[tg] = x1; gy1[tg] = y1; gx2[tg] = x2; gy2[tg] = y2;
        gar[tg] = ((x2 - x1) + 1.0f) * ((y2 - y1) + 1.0f);
        float best = p[5]; int bc = 0;
#pragma unroll
        for (int c = 1; c < 20; ++c) {      // first-max argmax (numpy semantics)
            float v = p[5 + c];
            if (v > best) { best = v; bc = c; }
        }
        gcv[tg] = (uint32)bc;
        vbits |= (cf >= 0.5f ? 1u : 0u) << e;
    }
    vb[t] = vbits;
    __syncthreads();
    if (t < 64) {
        uint32 w4 = vb[t * 4] | (vb[t * 4 + 1] << 8) | (vb[t * 4 + 2] << 16) | (vb[t * 4 + 3] << 24);
        vwords[b * 64 + t] = w4;
    }
}

// ---------------- NMS stage 2: suppression bitmask build ----------------
// Strict-upper-triangle only (bits j<=i unwritten/garbage: provably never
// consumed by scan). Block = strip pair (p, 31-p); 16 waves = 2 strips,
// 8 rows/wave (waves 0-7: strip p, waves 8-15: strip 31-p) -> constant
// 33 round-sum per block. SoA b32 LDS (conflict-free consecutive-lane
// reads); col data register-double-buffered; areas computed in-register.
// Exact div-free IoU threshold (R5 proof): round(inter/denom) >= 0.4f
// <=> (double)inter > KMID*(double)denom (25+24-bit product exact in f64).
#define KMID (13421772.5 / 33554432.0)
__global__ __launch_bounds__(1024) void build_kernel(const float* __restrict__ gx1,
                                                     const float* __restrict__ gy1,
                                                     const float* __restrict__ gx2,
                                                     const float* __restrict__ gy2,
                                                     const float* __restrict__ gar,
                                                     const uint32* __restrict__ gcv,
                                                     uint32* __restrict__ rowmask) {
    __shared__ float  x1s[TOPK], y1s[TOPK], x2s[TOPK], y2s[TOPK];  // 32 KiB
    __shared__ uint32 clss[TOPK];                                  // 8 KiB
    int bt   = blockIdx.y;
    int pr   = blockIdx.x;          // pair 0..15
    int tid  = threadIdx.x;
    int lane = tid & 63;
    int wv   = tid >> 6;            // wave 0..15
    int base = bt * TOPK;
    u64* rm64 = (u64*)(rowmask + (size_t)base * NWORD);   // [row][32] u64

    for (int j = tid; j < TOPK; j += 1024) {
        int g = base + j;
        x1s[j] = gx1[g]; y1s[j] = gy1[g]; x2s[j] = gx2[g]; y2s[j] = gy2[g];
        clss[j] = gcv[g] & 0xffu;
    }
    __syncthreads();

    int r  = (wv >> 3) ? (31 - pr) : pr;   // strip index
    int i0 = r * 64 + (wv & 7) * 8;        // this wave's 8 rows

    float rx1[8], ry1[8], rx2[8], ry2[8], rar[8];
    uint32 rcl[8];
#pragma unroll
    for (int k = 0; k < 8; ++k) {
        rx1[k] = x1s[i0 + k]; ry1[k] = y1s[i0 + k];
        rx2[k] = x2s[i0 + k]; ry2[k] = y2s[i0 + k];
        rar[k] = ((rx2[k] - rx1[k]) + 1.0f) * ((ry2[k] - ry1[k]) + 1.0f);
        rcl[k] = clss[i0 + k];
    }

    // column registers (double-buffered)
    int j0 = r * 64 + lane;
    float cx1 = x1s[j0], cy1 = y1s[j0], cx2 = x2s[j0], cy2 = y2s[j0];
    uint32 cc = clss[j0];

    for (int cg = r; cg < 32; ++cg) {
        float nx1 = 0.f, ny1 = 0.f, nx2 = 0.f, ny2 = 0.f; uint32 nc = 0;
        if (cg + 1 < 32) {      // prefetch next column group
            int nj = (cg + 1) * 64 + lane;
            nx1 = x1s[nj]; ny1 = y1s[nj]; nx2 = x2s[nj]; ny2 = y2s[nj];
            nc = clss[nj];
        }
        float car = ((cx2 - cx1) + 1.0f) * ((cy2 - cy1) + 1.0f);
        u64 bal[8];
#pragma unroll
        for (int k = 0; k < 8; ++k) {
            float ix1 = fmaxf(rx1[k], cx1);
            float iy1 = fmaxf(ry1[k], cy1);
            float ix2 = fminf(rx2[k], cx2);
            float iy2 = fminf(ry2[k], cy2);
            float iw = fmaxf((ix2 - ix1) + 1.0f, 0.0f);
            float ih = fmaxf((iy2 - iy1) + 1.0f, 0.0f);
            float inter = iw * ih;
            float denom = ((rar[k] + car) - inter) + 1e-16f;
            bool cond = ((double)inter > KMID * (double)denom) && (cc == rcl[k]);
            bal[k] = __ballot(cond);
        }
        u64 v = bal[0];
#pragma unroll
        for (int k = 1; k < 8; ++k) if (lane == k) v = bal[k];
        if (lane < 8) rm64[(size_t)(i0 + lane) * 32 + cg] = v;
        cx1 = nx1; cy1 = ny1; cx2 = nx2; cy2 = ny2; cc = nc;
    }
}

// ---------------- NMS stage 3: group-batched greedy scan ----------------
// (unchanged from R9 — see comments there)
__global__ __launch_bounds__(1024) void scan_kernel(const uint32* __restrict__ rowmask,
                                                    const uint32* __restrict__ vwords,
                                                    float* __restrict__ keepf) {
    __shared__ uint32 buf[2][64 * CHP];   // 2 x 66,560 B
    int bt  = blockIdx.x;
    int tid = threadIdx.x;
    int wv  = tid >> 6;
    int l   = tid & 63;
    const uint32* rm = rowmask + (size_t)bt * TOPK * NWORD;

    uint32 supp = 0, keepw = 0;
    if (wv == 0) supp = ~vwords[bt * 64 + l];

    if (wv > 0) {
        int ctid = tid - 64;
        uint32* dst = buf[0];
        for (int o = ctid; o < 4096; o += 960) {
            int q = o >> 8, r = o & 255;
            uint4 v = *(const uint4*)(rm + (size_t)r * NWORD + q * 4);
            int sg = r >> 5;
            uint32 smsk = ~((2u << (r & 31)) - 1u);
            uint32 vv[4] = {v.x, v.y, v.z, v.w};
#pragma unroll
            for (int j = 0; j < 4; ++j) {
                int w = 4 * q + j;
                uint32 x = vv[j];
                if (w == sg) x &= smsk;
                dst[w * CHP + r] = x;
            }
        }
    }
    __syncthreads();

    for (int c = 0; c < NCHUNK; ++c) {
        if (wv > 0) {
            if (c + 1 < NCHUNK) {
                int ctid = tid - 64;
                const uint32* src = rm + (size_t)(c + 1) * CH * NWORD;
                uint32* dst = buf[(c + 1) & 1];
                for (int o = ctid; o < 4096; o += 960) {
                    int q = o >> 8, r = o & 255;
                    uint4 v = *(const uint4*)(src + (size_t)r * NWORD + q * 4);
                    int gi = (c + 1) * CH + r;
                    int sg = gi >> 5;
                    uint32 smsk = ~((2u << (gi & 31)) - 1u);
                    uint32 vv[4] = {v.x, v.y, v.z, v.w};
#pragma unroll
                    for (int j = 0; j < 4; ++j) {
                        int w = 4 * q + j;
                        uint32 x = vv[j];
                        if (w == sg) x &= smsk;
                        dst[w * CHP + r] = x;
                    }
                }
            }
        } else {
            const uint32* bp = buf[c & 1];
            uint4 sq[8];
            {
                int g0 = c * GPC;
                const uint4* sp = (const uint4*)(bp + g0 * CHP);
#pragma unroll
                for (int q = 0; q < 8; ++q) sq[q] = sp[q];
            }
            for (int gl = 0; gl < GPC; ++gl) {
                int g = c * GPC + gl;
                uint4 rwq[8];
                const uint4* rp = (const uint4*)(bp + l * CHP + gl * 32);
#pragma unroll
                for (int q = 0; q < 8; ++q) rwq[q] = rp[q];
                uint32 cur = __builtin_amdgcn_readlane(supp, g);
#pragma unroll
                for (int q = 0; q < 8; ++q) {
                    uint32 s0 = sq[q].x, s1 = sq[q].y, s2 = sq[q].z, s3 = sq[q].w;
                    int k = q * 4;
                    cur |= s0 & ((((cur >> (k + 0)) & 1u)) - 1u);
                    cur |= s1 & ((((cur >> (k + 1)) & 1u)) - 1u);
                    cur |= s2 & ((((cur >> (k + 2)) & 1u)) - 1u);
                    cur |= s3 & ((((cur >> (k + 3)) & 1u)) - 1u);
                }
                uint32 keep = ~cur;
                if (l == g) keepw = keep;
                if (gl + 1 < GPC) {
                    const uint4* sp = (const uint4*)(bp + (g + 1) * CHP + (gl + 1) * 32);
#pragma unroll
                    for (int q = 0; q < 8; ++q) sq[q] = sp[q];
                }
                uint32 upd = 0;
#pragma unroll
                for (int q = 0; q < 8; ++q) {
                    int k = q * 4;
                    upd |= rwq[q].x & (uint32)(((int)(keep << (31 - (k + 0)))) >> 31);
                    upd |= rwq[q].y & (uint32)(((int)(keep << (31 - (k + 1)))) >> 31);
                    upd |= rwq[q].z & (uint32)(((int)(keep << (31 - (k + 2)))) >> 31);
                    upd |= rwq[q].w & (uint32)(((int)(keep << (31 - (k + 3)))) >> 31);
                }
                supp |= upd;
            }
        }
        __syncthreads();
    }

    if (wv == 0) {
#pragma unroll
        for (int k = 0; k < 32; ++k)
            keepf[bt * TOPK + l * 32 + k] = (float)((keepw >> k) & 1u);
    }
}

extern "C" void kernel_launch(void* const* d_in, const int* in_sizes, int n_in,
                              void* d_out, int out_size, void* d_ws, size_t ws_size,
                              hipStream_t stream) {
    const float* inp     = (const float*)d_in[0];
    const float* anchors = (const float*)d_in[1];
    float* out   = (float*)d_out;                        // [B, N, 25]
    float* topf  = out  + (size_t)B * NCAND * CATTR;     // [B, 2048] indices as float
    float* keepf = topf + (size_t)B * TOPK;              // [B, 2048] 0/1 as float

    // workspace layout
    float*  cws = (float*)d_ws;                          // [B, NCAND] conf
    float*  gx1 = cws + B * NCAND;
    float*  gy1 = gx1 + B * TOPK;
    float*  gx2 = gy1 + B * TOPK;
    float*  gy2 = gx2 + B * TOPK;
    float*  gar = gy2 + B * TOPK;
    uint32* gcv = (uint32*)(gar + B * TOPK);
    uint32* rowmask = gcv + B * TOPK;                    // 16*2048*64 u32 = 8 MiB
    uint32* vwords  = rowmask + (size_t)B * TOPK * NWORD;
    // sort scratch aliases onto rowmask (sort completes before build writes)
    u64* runs = (u64*)rowmask;                           // 1 MiB
    u64* half = runs + (size_t)B * 4 * 2048;             // 0.5 MiB

    decode_kernel<<<(B * NCAND) / 256, 256, 0, stream>>>(inp, anchors, out, cws);
    sort1_kernel<<<B * 4, 256, 0, stream>>>(cws, runs);
    sort2_kernel<<<B * 2, 256, 0, stream>>>(runs, half);
    sort3_kernel<<<B, 256, 0, stream>>>(half, out, topf, gx1, gy1, gx2, gy2, gar, gcv, vwords);
    build_kernel<<<dim3(16, B), 1024, 0, stream>>>(gx1, gy1, gx2, gy2, gar, gcv, rowmask);
    scan_kernel<<<B, 1024, 0, stream>>>(rowmask, vwords, keepf);
}

// Round 11
// 186.685 us; speedup vs baseline: 1.3785x; 1.0530x over previous
//
#include <hip/hip_runtime.h>

#pragma clang fp contract(off)

#define B 16
#define A 3
#define HGT 52
#define WID 52
#define HW 2704
#define NCAND 8112   // A*HW
#define CATTR 25
#define TOPK 2048
#define NWORD 64     // 64 u32 words x 32 bits = 2048 cols
#define CH 256       // rows per scan chunk
#define NCHUNK (TOPK / CH)   // 8
#define GPC (CH / 32)        // 8 groups per chunk
#define CHP 260      // padded chunk-row stride (words); %4==0 keeps b128 align
#define EPT 8        // sort: elements per thread

typedef unsigned int uint32;
typedef unsigned long long u64;

// ---------------- decode ----------------
__global__ __launch_bounds__(256) void decode_kernel(const float* __restrict__ inp,
                                                     const float* __restrict__ anchors,
                                                     float* __restrict__ out,
                                                     float* __restrict__ cws) {
    __shared__ float sm[256 * CATTR];   // 25.6 KiB, candidate-major == out order
    int tid = threadIdx.x;
    int t = blockIdx.x * 256 + tid;     // < B*NCAND (129792 = 507*256 exactly)
    int b  = t / NCAND;
    int n  = t - b * NCAND;
    int a  = n / HW;
    int hw = n - a * HW;
    int gy = hw / WID;
    int gx = hw - gy * WID;
    const float* ip = inp + ((size_t)(b * (A * CATTR) + a * CATTR)) * HW + hw;
    float* sp = sm + tid * CATTR;

    float p0 = ip[0 * HW], p1 = ip[1 * HW], p2 = ip[2 * HW], p3 = ip[3 * HW], p4 = ip[4 * HW];
    float sx = 1.0f / (1.0f + expf(-p0));
    float sy = 1.0f / (1.0f + expf(-p1));
    float bx = (sx + (float)gx) * 8.0f;   // stride = 8 exactly
    float by = (sy + (float)gy) * 8.0f;
    float bw = expf(p2) * anchors[a * 2 + 0];   // (anchor/8)*8 exact
    float bh = expf(p3) * anchors[a * 2 + 1];
    float cf = 1.0f / (1.0f + expf(-p4));
    sp[0] = bx; sp[1] = by; sp[2] = bw; sp[3] = bh; sp[4] = cf;
    cws[t] = cf;   // contiguous conf for the sort
#pragma unroll
    for (int c = 0; c < 20; ++c) {
        float v = ip[(5 + c) * HW];
        sp[5 + c] = 1.0f / (1.0f + expf(-v));
    }
    __syncthreads();
    const float4* sm4 = (const float4*)sm;
    float4* o4 = (float4*)(out + (size_t)blockIdx.x * 256 * CATTR);
#pragma unroll
    for (int k = 0; k < 6; ++k) o4[k * 256 + tid] = sm4[k * 256 + tid];
    if (tid < 64) o4[1536 + tid] = sm4[1536 + tid];
}

// ---------------- sort helpers ----------------
// key = (~(conf_bits|sign) << 32) | idx ; ascending == conf desc, idx asc.
__device__ __forceinline__ void cexd(u64& a, u64& b, bool up) {
    if ((a > b) == up) { u64 tmp = a; a = b; b = tmp; }
}

__device__ __forceinline__ u64 sel(u64 k, u64 o, bool kmin) {
    return kmin ? (k < o ? k : o) : (k > o ? k : o);
}

// bitonic merge of a 2048-element bitonic sequence to ascending order.
__device__ __forceinline__ void bitonic_merge_2048(u64 key[EPT], u64* mb, int t) {
    for (unsigned j = 1024; j >= 8; j >>= 1) {
        unsigned m = j >> 3;
        bool kmin = ((t & m) == 0);
        if (m >= 64) {
            __syncthreads();
#pragma unroll
            for (int e = 0; e < EPT; ++e) mb[e * 256 + t] = key[e];
            __syncthreads();
            int pt = t ^ (int)m;
#pragma unroll
            for (int e = 0; e < EPT; ++e) key[e] = sel(key[e], mb[e * 256 + pt], kmin);
        } else {
#pragma unroll
            for (int e = 0; e < EPT; ++e) {
                u64 o = __shfl_xor(key[e], (int)m);
                key[e] = sel(key[e], o, kmin);
            }
        }
    }
    cexd(key[0], key[4], true); cexd(key[1], key[5], true);
    cexd(key[2], key[6], true); cexd(key[3], key[7], true);
    cexd(key[0], key[2], true); cexd(key[1], key[3], true);
    cexd(key[4], key[6], true); cexd(key[5], key[7], true);
    cexd(key[0], key[1], true); cexd(key[2], key[3], true);
    cexd(key[4], key[5], true); cexd(key[6], key[7], true);
}

// ---------------- S1: sort each 2048-chunk ascending ----------------
__global__ __launch_bounds__(256) void sort1_kernel(const float* __restrict__ conf,
                                                    u64* __restrict__ runs) {
    __shared__ u64 mb[2048];   // 16 KiB SoA mailbox
    int blk = blockIdx.x;
    int b = blk >> 2, c = blk & 3;
    int t = threadIdx.x;
    int base = t * EPT;               // local 0..2047
    int gbase = c * 2048 + base;      // candidate index in batch
    const float* cp = conf + b * NCAND;

    u64 key[EPT];
    if (gbase + EPT <= NCAND) {
        const float4* cp4 = (const float4*)(cp + gbase);
        float4 c0 = cp4[0], c1 = cp4[1];
        float cf[EPT] = {c0.x, c0.y, c0.z, c0.w, c1.x, c1.y, c1.z, c1.w};
#pragma unroll
        for (int e = 0; e < EPT; ++e) {
            unsigned bits = __float_as_uint(cf[e]) | 0x80000000u;
            key[e] = ((u64)(~bits) << 32) | (unsigned)(gbase + e);
        }
    } else {
#pragma unroll
        for (int e = 0; e < EPT; ++e) {
            int idx = gbase + e;
            if (idx < NCAND) {
                unsigned bits = __float_as_uint(cp[idx]) | 0x80000000u;
                key[e] = ((u64)(~bits) << 32) | (unsigned)idx;
            } else key[e] = ~0ull;   // pad sorts last
        }
    }

    cexd(key[0], key[1], true); cexd(key[2], key[3], false);
    cexd(key[4], key[5], true); cexd(key[6], key[7], false);

    cexd(key[0], key[2], true);  cexd(key[1], key[3], true);
    cexd(key[4], key[6], false); cexd(key[5], key[7], false);
    cexd(key[0], key[1], true);  cexd(key[2], key[3], true);
    cexd(key[4], key[5], false); cexd(key[6], key[7], false);

    bool up8 = ((t & 1) == 0);
    cexd(key[0], key[4], up8); cexd(key[1], key[5], up8);
    cexd(key[2], key[6], up8); cexd(key[3], key[7], up8);
    cexd(key[0], key[2], up8); cexd(key[1], key[3], up8);
    cexd(key[4], key[6], up8); cexd(key[5], key[7], up8);
    cexd(key[0], key[1], up8); cexd(key[2], key[3], up8);
    cexd(key[4], key[5], up8); cexd(key[6], key[7], up8);

    for (unsigned k = 16; k <= 2048; k <<= 1) {
        bool up = (((unsigned)base & k) == 0);
        for (unsigned j = k >> 1; j >= 8; j >>= 1) {
            unsigned m = j >> 3;
            bool kmin = (up == ((t & m) == 0));
            if (m >= 64) {
                __syncthreads();
#pragma unroll
                for (int e = 0; e < EPT; ++e) mb[e * 256 + t] = key[e];
                __syncthreads();
                int pt = t ^ (int)m;
#pragma unroll
                for (int e = 0; e < EPT; ++e) key[e] = sel(key[e], mb[e * 256 + pt], kmin);
            } else {
#pragma unroll
                for (int e = 0; e < EPT; ++e) {
                    u64 o = __shfl_xor(key[e], (int)m);
                    key[e] = sel(key[e], o, kmin);
                }
            }
        }
        cexd(key[0], key[4], up); cexd(key[1], key[5], up);
        cexd(key[2], key[6], up); cexd(key[3], key[7], up);
        cexd(key[0], key[2], up); cexd(key[1], key[3], up);
        cexd(key[4], key[6], up); cexd(key[5], key[7], up);
        cexd(key[0], key[1], up); cexd(key[2], key[3], up);
        cexd(key[4], key[5], up); cexd(key[6], key[7], up);
    }

    u64* R = runs + ((size_t)b * 4 + c) * 2048;
#pragma unroll
    for (int e = 0; e < EPT; ++e) R[base + e] = key[e];
}

// ---------------- S2: merge+prune two 2048-runs -> sorted 2048 -------
__global__ __launch_bounds__(256) void sort2_kernel(const u64* __restrict__ runs,
                                                    u64* __restrict__ half) {
    __shared__ u64 mb[2048];
    int blk = blockIdx.x;
    int b = blk >> 1, p = blk & 1;
    int t = threadIdx.x;
    int base = t * EPT;
    const u64* Av = runs + ((size_t)b * 4 + p * 2) * 2048;
    const u64* Bv = Av + 2048;

    u64 key[EPT];
#pragma unroll
    for (int e = 0; e < EPT; ++e) {
        u64 a = Av[base + e];
        u64 o = Bv[2047 - (base + e)];
        key[e] = a < o ? a : o;
    }
    bitonic_merge_2048(key, mb, t);
    u64* H = half + ((size_t)b * 2 + p) * 2048;
#pragma unroll
    for (int e = 0; e < EPT; ++e) H[base + e] = key[e];
}

// ---------------- S3: final merge+prune -> topf + fused geometry ---------
__global__ __launch_bounds__(256) void sort3_kernel(const u64* __restrict__ half,
                                                    const float* __restrict__ out,
                                                    float* __restrict__ topf,
                                                    float* __restrict__ gx1,
                                                    float* __restrict__ gy1,
                                                    float* __restrict__ gx2,
                                                    float* __restrict__ gy2,
                                                    float* __restrict__ gar,
                                                    uint32* __restrict__ gcv,
                                                    uint32* __restrict__ vwords) {
    __shared__ u64 mb[2048];
    __shared__ uint32 vb[256];
    int b = blockIdx.x;
    int t = threadIdx.x;
    int base = t * EPT;
    const u64* Av = half + (size_t)b * 2 * 2048;
    const u64* Bv = Av + 2048;

    u64 key[EPT];
#pragma unroll
    for (int e = 0; e < EPT; ++e) {
        u64 a = Av[base + e];
        u64 o = Bv[2047 - (base + e)];
        key[e] = a < o ? a : o;
    }
    bitonic_merge_2048(key, mb, t);

    const float* ob = out + (size_t)b * NCAND * CATTR;
    uint32 vbits = 0;
#pragma unroll
    for (int e = 0; e < EPT; ++e) {
        uint32 idx = (uint32)(key[e] & 0xFFFFFFFFu);
        int tg = b * TOPK + base + e;
        topf[tg] = (float)idx;
        const float* p = ob + (size_t)idx * CATTR;
        float cx = p[0], cy = p[1], w = p[2], h = p[3], cf = p[4];
        float hw_ = w * 0.5f, hh_ = h * 0.5f;  // w/2 exact
        float x1 = cx - hw_, y1 = cy - hh_, x2 = cx + hw_, y2 = cy + hh_;
        gx1[tg] = x1; gy1[tg] = y1; gx2[tg] = x2; gy2[tg] = y2;
        gar[tg] = ((x2 - x1) + 1.0f) * ((y2 - y1) + 1.0f);
        float best = p[5]; int bc = 0;
#pragma unroll
        for (int c = 1; c < 20; ++c) {      // first-max argmax (numpy semantics)
            float v = p[5 + c];
            if (v > best) { best = v; bc = c; }
        }
        gcv[tg] = (uint32)bc;
        vbits |= (cf >= 0.5f ? 1u : 0u) << e;
    }
    vb[t] = vbits;
    __syncthreads();
    if (t < 64) {
        uint32 w4 = vb[t * 4] | (vb[t * 4 + 1] << 8) | (vb[t * 4 + 2] << 16) | (vb[t * 4 + 3] << 24);
        vwords[b * 64 + t] = w4;
    }
}

// ---------------- NMS stage 2: suppression bitmask build ----------------
// (unchanged from R10 — strict upper triangle, SoA b32 LDS, 8 rows/wave,
//  div-free exact IoU threshold; see R5/R9 notes)
#define KMID (13421772.5 / 33554432.0)
__global__ __launch_bounds__(1024) void build_kernel(const float* __restrict__ gx1,
                                                     const float* __restrict__ gy1,
                                                     const float* __restrict__ gx2,
                                                     const float* __restrict__ gy2,
                                                     const float* __restrict__ gar,
                                                     const uint32* __restrict__ gcv,
                                                     uint32* __restrict__ rowmask) {
    __shared__ float  x1s[TOPK], y1s[TOPK], x2s[TOPK], y2s[TOPK];  // 32 KiB
    __shared__ uint32 clss[TOPK];                                  // 8 KiB
    int bt   = blockIdx.y;
    int pr   = blockIdx.x;          // pair 0..15
    int tid  = threadIdx.x;
    int lane = tid & 63;
    int wv   = tid >> 6;            // wave 0..15
    int base = bt * TOPK;
    u64* rm64 = (u64*)(rowmask + (size_t)base * NWORD);   // [row][32] u64

    for (int j = tid; j < TOPK; j += 1024) {
        int g = base + j;
        x1s[j] = gx1[g]; y1s[j] = gy1[g]; x2s[j] = gx2[g]; y2s[j] = gy2[g];
        clss[j] = gcv[g] & 0xffu;
    }
    __syncthreads();

    int r  = (wv >> 3) ? (31 - pr) : pr;   // strip index
    int i0 = r * 64 + (wv & 7) * 8;        // this wave's 8 rows

    float rx1[8], ry1[8], rx2[8], ry2[8], rar[8];
    uint32 rcl[8];
#pragma unroll
    for (int k = 0; k < 8; ++k) {
        rx1[k] = x1s[i0 + k]; ry1[k] = y1s[i0 + k];
        rx2[k] = x2s[i0 + k]; ry2[k] = y2s[i0 + k];
        rar[k] = ((rx2[k] - rx1[k]) + 1.0f) * ((ry2[k] - ry1[k]) + 1.0f);
        rcl[k] = clss[i0 + k];
    }

    int j0 = r * 64 + lane;
    float cx1 = x1s[j0], cy1 = y1s[j0], cx2 = x2s[j0], cy2 = y2s[j0];
    uint32 cc = clss[j0];

    for (int cg = r; cg < 32; ++cg) {
        float nx1 = 0.f, ny1 = 0.f, nx2 = 0.f, ny2 = 0.f; uint32 nc = 0;
        if (cg + 1 < 32) {      // prefetch next column group
            int nj = (cg + 1) * 64 + lane;
            nx1 = x1s[nj]; ny1 = y1s[nj]; nx2 = x2s[nj]; ny2 = y2s[nj];
            nc = clss[nj];
        }
        float car = ((cx2 - cx1) + 1.0f) * ((cy2 - cy1) + 1.0f);
        u64 bal[8];
#pragma unroll
        for (int k = 0; k < 8; ++k) {
            float ix1 = fmaxf(rx1[k], cx1);
            float iy1 = fmaxf(ry1[k], cy1);
            float ix2 = fminf(rx2[k], cx2);
            float iy2 = fminf(ry2[k], cy2);
            float iw = fmaxf((ix2 - ix1) + 1.0f, 0.0f);
            float ih = fmaxf((iy2 - iy1) + 1.0f, 0.0f);
            float inter = iw * ih;
            float denom = ((rar[k] + car) - inter) + 1e-16f;
            bool cond = ((double)inter > KMID * (double)denom) && (cc == rcl[k]);
            bal[k] = __ballot(cond);
        }
        u64 v = bal[0];
#pragma unroll
        for (int k = 1; k < 8; ++k) if (lane == k) v = bal[k];
        if (lane < 8) rm64[(size_t)(i0 + lane) * 32 + cg] = v;
        cx1 = nx1; cy1 = ny1; cx2 = nx2; cy2 = ny2; cc = nc;
    }
}

// ---------------- NMS scan copy helper ----------------
// Copy chunk cc (rows cc*CH..+CH) into dst, TRANSPOSED [word][row], words
// 16*(cc>>1)..63 only (words < 8*cc never consumed -- R5/R6 proof; stale
// LDS below that is harmless). Lane layout: r = o>>2, q4 = o&3; each lane
// loads 4 consecutive uint4 = 64 B; 4 lanes = full 256-B row -> perfectly
// coalesced global reads. Diagonal self-words scrubbed (bits <= row%32).
// LDS writes: bank = (4j + r) % 32, 4-way conflict (1.58x) -- off critical
// path (copy waves).
__device__ __forceinline__ void copy_chunk(const uint32* __restrict__ rm,
                                           uint32* __restrict__ dst,
                                           int cc, int ctid) {
    const uint32* src = rm + (size_t)cc * CH * NWORD;
    int q4min = cc >> 1;
    for (int o = ctid; o < 1024; o += 960) {
        int q4 = o & 3, r = o >> 2;
        if (q4 < q4min) continue;
        const uint4* s4 = (const uint4*)(src + (size_t)r * NWORD + q4 * 16);
        uint4 v0 = s4[0], v1 = s4[1], v2 = s4[2], v3 = s4[3];
        int gi = cc * CH + r;
        int sg = gi >> 5;                          // diagonal word index
        uint32 smsk = ~((2u << (gi & 31)) - 1u);
        uint32 wv[16] = {v0.x, v0.y, v0.z, v0.w, v1.x, v1.y, v1.z, v1.w,
                         v2.x, v2.y, v2.z, v2.w, v3.x, v3.y, v3.z, v3.w};
        int wbase = q4 * 16;
        uint32* dp = dst + r;
#pragma unroll
        for (int j = 0; j < 16; ++j) {
            uint32 x = wv[j];
            if (wbase + j == sg) x &= smsk;        // branchless cndmask
            dp[(wbase + j) * CHP] = x;
        }
    }
}

// ---------------- NMS stage 3: group-batched greedy scan ----------------
// 1 block/batch, 1024 thr. Wave 0 scans; waves 1-15 stream chunks into a
// double-buffered transposed LDS (see copy_chunk). Per 32-candidate group:
// 8x broadcast b128 self-words -> monotone in-register resolve ->
// keep = ~cur -> masked OR of all 32 rows (8x b128/lane, aggregate
// conflict-free). Garbage at j<=i provably never consumed.
__global__ __launch_bounds__(1024) void scan_kernel(const uint32* __restrict__ rowmask,
                                                    const uint32* __restrict__ vwords,
                                                    float* __restrict__ keepf) {
    __shared__ uint32 buf[2][64 * CHP];   // 2 x 66,560 B
    int bt  = blockIdx.x;
    int tid = threadIdx.x;
    int wv  = tid >> 6;
    int l   = tid & 63;
    const uint32* rm = rowmask + (size_t)bt * TOPK * NWORD;

    uint32 supp = 0, keepw = 0;
    if (wv == 0) supp = ~vwords[bt * 64 + l];

    if (wv > 0) copy_chunk(rm, buf[0], 0, tid - 64);
    __syncthreads();

    for (int c = 0; c < NCHUNK; ++c) {
        if (wv > 0) {
            if (c + 1 < NCHUNK) copy_chunk(rm, buf[(c + 1) & 1], c + 1, tid - 64);
        } else {
            const uint32* bp = buf[c & 1];
            uint4 sq[8];
            {
                int g0 = c * GPC;
                const uint4* sp = (const uint4*)(bp + g0 * CHP);
#pragma unroll
                for (int q = 0; q < 8; ++q) sq[q] = sp[q];
            }
            for (int gl = 0; gl < GPC; ++gl) {
                int g = c * GPC + gl;
                uint4 rwq[8];
                const uint4* rp = (const uint4*)(bp + l * CHP + gl * 32);
#pragma unroll
                for (int q = 0; q < 8; ++q) rwq[q] = rp[q];
                uint32 cur = __builtin_amdgcn_readlane(supp, g);
#pragma unroll
                for (int q = 0; q < 8; ++q) {
                    uint32 s0 = sq[q].x, s1 = sq[q].y, s2 = sq[q].z, s3 = sq[q].w;
                    int k = q * 4;
                    cur |= s0 & ((((cur >> (k + 0)) & 1u)) - 1u);
                    cur |= s1 & ((((cur >> (k + 1)) & 1u)) - 1u);
                    cur |= s2 & ((((cur >> (k + 2)) & 1u)) - 1u);
                    cur |= s3 & ((((cur >> (k + 3)) & 1u)) - 1u);
                }
                uint32 keep = ~cur;
                if (l == g) keepw = keep;
                if (gl + 1 < GPC) {
                    const uint4* sp = (const uint4*)(bp + (g + 1) * CHP + (gl + 1) * 32);
#pragma unroll
                    for (int q = 0; q < 8; ++q) sq[q] = sp[q];
                }
                uint32 upd = 0;
#pragma unroll
                for (int q = 0; q < 8; ++q) {
                    int k = q * 4;
                    upd |= rwq[q].x & (uint32)(((int)(keep << (31 - (k + 0)))) >> 31);
                    upd |= rwq[q].y & (uint32)(((int)(keep << (31 - (k + 1)))) >> 31);
                    upd |= rwq[q].z & (uint32)(((int)(keep << (31 - (k + 2)))) >> 31);
                    upd |= rwq[q].w & (uint32)(((int)(keep << (31 - (k + 3)))) >> 31);
                }
                supp |= upd;
            }
        }
        __syncthreads();
    }

    if (wv == 0) {
#pragma unroll
        for (int k = 0; k < 32; ++k)
            keepf[bt * TOPK + l * 32 + k] = (float)((keepw >> k) & 1u);
    }
}

extern "C" void kernel_launch(void* const* d_in, const int* in_sizes, int n_in,
                              void* d_out, int out_size, void* d_ws, size_t ws_size,
                              hipStream_t stream) {
    const float* inp     = (const float*)d_in[0];
    const float* anchors = (const float*)d_in[1];
    float* out   = (float*)d_out;                        // [B, N, 25]
    float* topf  = out  + (size_t)B * NCAND * CATTR;     // [B, 2048] indices as float
    float* keepf = topf + (size_t)B * TOPK;              // [B, 2048] 0/1 as float

    // workspace layout
    float*  cws = (float*)d_ws;                          // [B, NCAND] conf
    float*  gx1 = cws + B * NCAND;
    float*  gy1 = gx1 + B * TOPK;
    float*  gx2 = gy1 + B * TOPK;
    float*  gy2 = gx2 + B * TOPK;
    float*  gar = gy2 + B * TOPK;
    uint32* gcv = (uint32*)(gar + B * TOPK);
    uint32* rowmask = gcv + B * TOPK;                    // 16*2048*64 u32 = 8 MiB
    uint32* vwords  = rowmask + (size_t)B * TOPK * NWORD;
    // sort scratch aliases onto rowmask (sort completes before build writes)
    u64* runs = (u64*)rowmask;                           // 1 MiB
    u64* half = runs + (size_t)B * 4 * 2048;             // 0.5 MiB

    decode_kernel<<<(B * NCAND) / 256, 256, 0, stream>>>(inp, anchors, out, cws);
    sort1_kernel<<<B * 4, 256, 0, stream>>>(cws, runs);
    sort2_kernel<<<B * 2, 256, 0, stream>>>(runs, half);
    sort3_kernel<<<B, 256, 0, stream>>>(half, out, topf, gx1, gy1, gx2, gy2, gar, gcv, vwords);
    build_kernel<<<dim3(16, B), 1024, 0, stream>>>(gx1, gy1, gx2, gy2, gar, gcv, rowmask);
    scan_kernel<<<B, 1024, 0, stream>>>(rowmask, vwords, keepf);
}

// Round 12
// 186.550 us; speedup vs baseline: 1.3794x; 1.0007x over previous
//
#include <hip/hip_runtime.h>

#pragma clang fp contract(off)

#define B 16
#define A 3
#define HGT 52
#define WID 52
#define HW 2704
#define NCAND 8112   // A*HW
#define CATTR 25
#define TOPK 2048
#define NWORD 64     // 64 u32 words x 32 bits = 2048 cols
#define CH 256       // rows per scan chunk
#define NCHUNK (TOPK / CH)   // 8
#define GPC (CH / 32)        // 8 groups per chunk
#define CHP 260      // padded chunk-row stride (words); %4==0 keeps b128 align
#define EPT 8        // sort: elements per thread

typedef unsigned int uint32;
typedef unsigned long long u64;

// ---------------- decode ----------------
__global__ __launch_bounds__(256) void decode_kernel(const float* __restrict__ inp,
                                                     const float* __restrict__ anchors,
                                                     float* __restrict__ out,
                                                     float* __restrict__ cws) {
    __shared__ float sm[256 * CATTR];   // 25.6 KiB, candidate-major == out order
    int tid = threadIdx.x;
    int t = blockIdx.x * 256 + tid;     // < B*NCAND (129792 = 507*256 exactly)
    int b  = t / NCAND;
    int n  = t - b * NCAND;
    int a  = n / HW;
    int hw = n - a * HW;
    int gy = hw / WID;
    int gx = hw - gy * WID;
    const float* ip = inp + ((size_t)(b * (A * CATTR) + a * CATTR)) * HW + hw;
    float* sp = sm + tid * CATTR;

    float p0 = ip[0 * HW], p1 = ip[1 * HW], p2 = ip[2 * HW], p3 = ip[3 * HW], p4 = ip[4 * HW];
    float sx = 1.0f / (1.0f + expf(-p0));
    float sy = 1.0f / (1.0f + expf(-p1));
    float bx = (sx + (float)gx) * 8.0f;   // stride = 8 exactly
    float by = (sy + (float)gy) * 8.0f;
    float bw = expf(p2) * anchors[a * 2 + 0];   // (anchor/8)*8 exact
    float bh = expf(p3) * anchors[a * 2 + 1];
    float cf = 1.0f / (1.0f + expf(-p4));
    sp[0] = bx; sp[1] = by; sp[2] = bw; sp[3] = bh; sp[4] = cf;
    cws[t] = cf;   // contiguous conf for the sort
#pragma unroll
    for (int c = 0; c < 20; ++c) {
        float v = ip[(5 + c) * HW];
        sp[5 + c] = 1.0f / (1.0f + expf(-v));
    }
    __syncthreads();
    const float4* sm4 = (const float4*)sm;
    float4* o4 = (float4*)(out + (size_t)blockIdx.x * 256 * CATTR);
#pragma unroll
    for (int k = 0; k < 6; ++k) o4[k * 256 + tid] = sm4[k * 256 + tid];
    if (tid < 64) o4[1536 + tid] = sm4[1536 + tid];
}

// ---------------- sort helpers ----------------
// key = (~(conf_bits|sign) << 32) | idx ; ascending == conf desc, idx asc.
__device__ __forceinline__ void cexd(u64& a, u64& b, bool up) {
    if ((a > b) == up) { u64 tmp = a; a = b; b = tmp; }
}

__device__ __forceinline__ u64 sel(u64 k, u64 o, bool kmin) {
    return kmin ? (k < o ? k : o) : (k > o ? k : o);
}

// bitonic merge of a 2048-element bitonic sequence to ascending order.
__device__ __forceinline__ void bitonic_merge_2048(u64 key[EPT], u64* mb, int t) {
    for (unsigned j = 1024; j >= 8; j >>= 1) {
        unsigned m = j >> 3;
        bool kmin = ((t & m) == 0);
        if (m >= 64) {
            __syncthreads();
#pragma unroll
            for (int e = 0; e < EPT; ++e) mb[e * 256 + t] = key[e];
            __syncthreads();
            int pt = t ^ (int)m;
#pragma unroll
            for (int e = 0; e < EPT; ++e) key[e] = sel(key[e], mb[e * 256 + pt], kmin);
        } else {
#pragma unroll
            for (int e = 0; e < EPT; ++e) {
                u64 o = __shfl_xor(key[e], (int)m);
                key[e] = sel(key[e], o, kmin);
            }
        }
    }
    cexd(key[0], key[4], true); cexd(key[1], key[5], true);
    cexd(key[2], key[6], true); cexd(key[3], key[7], true);
    cexd(key[0], key[2], true); cexd(key[1], key[3], true);
    cexd(key[4], key[6], true); cexd(key[5], key[7], true);
    cexd(key[0], key[1], true); cexd(key[2], key[3], true);
    cexd(key[4], key[5], true); cexd(key[6], key[7], true);
}

// ---------------- S1: sort each 2048-chunk ascending ----------------
__global__ __launch_bounds__(256) void sort1_kernel(const float* __restrict__ conf,
                                                    u64* __restrict__ runs) {
    __shared__ u64 mb[2048];   // 16 KiB SoA mailbox
    int blk = blockIdx.x;
    int b = blk >> 2, c = blk & 3;
    int t = threadIdx.x;
    int base = t * EPT;               // local 0..2047
    int gbase = c * 2048 + base;      // candidate index in batch
    const float* cp = conf + b * NCAND;

    u64 key[EPT];
    if (gbase + EPT <= NCAND) {
        const float4* cp4 = (const float4*)(cp + gbase);
        float4 c0 = cp4[0], c1 = cp4[1];
        float cf[EPT] = {c0.x, c0.y, c0.z, c0.w, c1.x, c1.y, c1.z, c1.w};
#pragma unroll
        for (int e = 0; e < EPT; ++e) {
            unsigned bits = __float_as_uint(cf[e]) | 0x80000000u;
            key[e] = ((u64)(~bits) << 32) | (unsigned)(gbase + e);
        }
    } else {
#pragma unroll
        for (int e = 0; e < EPT; ++e) {
            int idx = gbase + e;
            if (idx < NCAND) {
                unsigned bits = __float_as_uint(cp[idx]) | 0x80000000u;
                key[e] = ((u64)(~bits) << 32) | (unsigned)idx;
            } else key[e] = ~0ull;   // pad sorts last
        }
    }

    cexd(key[0], key[1], true); cexd(key[2], key[3], false);
    cexd(key[4], key[5], true); cexd(key[6], key[7], false);

    cexd(key[0], key[2], true);  cexd(key[1], key[3], true);
    cexd(key[4], key[6], false); cexd(key[5], key[7], false);
    cexd(key[0], key[1], true);  cexd(key[2], key[3], true);
    cexd(key[4], key[5], false); cexd(key[6], key[7], false);

    bool up8 = ((t & 1) == 0);
    cexd(key[0], key[4], up8); cexd(key[1], key[5], up8);
    cexd(key[2], key[6], up8); cexd(key[3], key[7], up8);
    cexd(key[0], key[2], up8); cexd(key[1], key[3], up8);
    cexd(key[4], key[6], up8); cexd(key[5], key[7], up8);
    cexd(key[0], key[1], up8); cexd(key[2], key[3], up8);
    cexd(key[4], key[5], up8); cexd(key[6], key[7], up8);

    for (unsigned k = 16; k <= 2048; k <<= 1) {
        bool up = (((unsigned)base & k) == 0);
        for (unsigned j = k >> 1; j >= 8; j >>= 1) {
            unsigned m = j >> 3;
            bool kmin = (up == ((t & m) == 0));
            if (m >= 64) {
                __syncthreads();
#pragma unroll
                for (int e = 0; e < EPT; ++e) mb[e * 256 + t] = key[e];
                __syncthreads();
                int pt = t ^ (int)m;
#pragma unroll
                for (int e = 0; e < EPT; ++e) key[e] = sel(key[e], mb[e * 256 + pt], kmin);
            } else {
#pragma unroll
                for (int e = 0; e < EPT; ++e) {
                    u64 o = __shfl_xor(key[e], (int)m);
                    key[e] = sel(key[e], o, kmin);
                }
            }
        }
        cexd(key[0], key[4], up); cexd(key[1], key[5], up);
        cexd(key[2], key[6], up); cexd(key[3], key[7], up);
        cexd(key[0], key[2], up); cexd(key[1], key[3], up);
        cexd(key[4], key[6], up); cexd(key[5], key[7], up);
        cexd(key[0], key[1], up); cexd(key[2], key[3], up);
        cexd(key[4], key[5], up); cexd(key[6], key[7], up);
    }

    u64* R = runs + ((size_t)b * 4 + c) * 2048;
#pragma unroll
    for (int e = 0; e < EPT; ++e) R[base + e] = key[e];
}

// ---------------- S23: fused 4-run prune-merge tree -> topf + geometry ----
// One block per batch. H0 = lowermerge(r0,r1); H1 = lowermerge(r2,r3);
// final = lowermerge(H0, rev H1 via mailbox). Each lowermerge: prune
// c[i] = min(A[i], B[2047-i]) (lower half of the j=2048 bitonic exchange:
// the 2048 smallest keys of the union, bitonic) + bitonic_merge_2048.
// Saves the sort3 launch + the 0.5 MB half[] HBM round-trip.
__global__ __launch_bounds__(256) void sort23_kernel(const u64* __restrict__ runs,
                                                     const float* __restrict__ out,
                                                     float* __restrict__ topf,
                                                     float* __restrict__ gx1,
                                                     float* __restrict__ gy1,
                                                     float* __restrict__ gx2,
                                                     float* __restrict__ gy2,
                                                     float* __restrict__ gar,
                                                     uint32* __restrict__ gcv,
                                                     uint32* __restrict__ vwords) {
    __shared__ u64 mb[2048];
    __shared__ uint32 vb[256];
    int b = blockIdx.x;
    int t = threadIdx.x;
    int base = t * EPT;
    const u64* R0 = runs + (size_t)b * 4 * 2048;

    u64 ka[EPT], kb[EPT];
    // H0 = lower merge of run0, run1
#pragma unroll
    for (int e = 0; e < EPT; ++e) {
        u64 a = R0[base + e];
        u64 o = R0[2048 + 2047 - (base + e)];
        ka[e] = a < o ? a : o;
    }
    bitonic_merge_2048(ka, mb, t);
    // H1 = lower merge of run2, run3
#pragma unroll
    for (int e = 0; e < EPT; ++e) {
        u64 a = R0[2 * 2048 + base + e];
        u64 o = R0[3 * 2048 + 2047 - (base + e)];
        kb[e] = a < o ? a : o;
    }
    bitonic_merge_2048(kb, mb, t);
    // final = lower merge of H0, H1 (H1 reversed through the mailbox)
    __syncthreads();                 // all lanes done reading mb from merge 2
#pragma unroll
    for (int e = 0; e < EPT; ++e) mb[base + e] = kb[e];
    __syncthreads();
#pragma unroll
    for (int e = 0; e < EPT; ++e) {
        u64 o = mb[2047 - (base + e)];
        ka[e] = ka[e] < o ? ka[e] : o;
    }
    bitonic_merge_2048(ka, mb, t);   // internal leading barrier protects mb

    // ---- fused geometry tail (identical to old sort3) ----
    const float* ob = out + (size_t)b * NCAND * CATTR;
    uint32 vbits = 0;
#pragma unroll
    for (int e = 0; e < EPT; ++e) {
        uint32 idx = (uint32)(ka[e] & 0xFFFFFFFFu);
        int tg = b * TOPK + base + e;
        topf[tg] = (float)idx;
        const float* p = ob + (size_t)idx * CATTR;
        float cx = p[0], cy = p[1], w = p[2], h = p[3], cf = p[4];
        float hw_ = w * 0.5f, hh_ = h * 0.5f;  // w/2 exact
        float x1 = cx - hw_, y1 = cy - hh_, x2 = cx + hw_, y2 = cy + hh_;
        gx1[tg] = x1; gy1[tg] = y1; gx2[tg] = x2; gy2[tg] = y2;
        gar[tg] = ((x2 - x1) + 1.0f) * ((y2 - y1) + 1.0f);
        float best = p[5]; int bc = 0;
#pragma unroll
        for (int c = 1; c < 20; ++c) {      // first-max argmax (numpy semantics)
            float v = p[5 + c];
            if (v > best) { best = v; bc = c; }
        }
        gcv[tg] = (uint32)bc;
        vbits |= (cf >= 0.5f ? 1u : 0u) << e;
    }
    vb[t] = vbits;
    __syncthreads();
    if (t < 64) {
        uint32 w4 = vb[t * 4] | (vb[t * 4 + 1] << 8) | (vb[t * 4 + 2] << 16) | (vb[t * 4 + 3] << 24);
        vwords[b * 64 + t] = w4;
    }
}

// ---------------- NMS stage 2: suppression bitmask build ----------------
// (strict upper triangle, SoA b32 LDS, 8 rows/wave, div-free exact IoU
//  threshold; see R5/R9 notes)
#define KMID (13421772.5 / 33554432.0)
__global__ __launch_bounds__(1024) void build_kernel(const float* __restrict__ gx1,
                                                     const float* __restrict__ gy1,
                                                     const float* __restrict__ gx2,
                                                     const float* __restrict__ gy2,
                                                     const float* __restrict__ gar,
                                                     const uint32* __restrict__ gcv,
                                                     uint32* __restrict__ rowmask) {
    __shared__ float  x1s[TOPK], y1s[TOPK], x2s[TOPK], y2s[TOPK];  // 32 KiB
    __shared__ uint32 clss[TOPK];                                  // 8 KiB
    int bt   = blockIdx.y;
    int pr   = blockIdx.x;          // pair 0..15
    int tid  = threadIdx.x;
    int lane = tid & 63;
    int wv   = tid >> 6;            // wave 0..15
    int base = bt * TOPK;
    u64* rm64 = (u64*)(rowmask + (size_t)base * NWORD);   // [row][32] u64

    for (int j = tid; j < TOPK; j += 1024) {
        int g = base + j;
        x1s[j] = gx1[g]; y1s[j] = gy1[g]; x2s[j] = gx2[g]; y2s[j] = gy2[g];
        clss[j] = gcv[g] & 0xffu;
    }
    __syncthreads();

    int r  = (wv >> 3) ? (31 - pr) : pr;   // strip index
    int i0 = r * 64 + (wv & 7) * 8;        // this wave's 8 rows

    float rx1[8], ry1[8], rx2[8], ry2[8], rar[8];
    uint32 rcl[8];
#pragma unroll
    for (int k = 0; k < 8; ++k) {
        rx1[k] = x1s[i0 + k]; ry1[k] = y1s[i0 + k];
        rx2[k] = x2s[i0 + k]; ry2[k] = y2s[i0 + k];
        rar[k] = ((rx2[k] - rx1[k]) + 1.0f) * ((ry2[k] - ry1[k]) + 1.0f);
        rcl[k] = clss[i0 + k];
    }

    int j0 = r * 64 + lane;
    float cx1 = x1s[j0], cy1 = y1s[j0], cx2 = x2s[j0], cy2 = y2s[j0];
    uint32 cc = clss[j0];

    for (int cg = r; cg < 32; ++cg) {
        float nx1 = 0.f, ny1 = 0.f, nx2 = 0.f, ny2 = 0.f; uint32 nc = 0;
        if (cg + 1 < 32) {      // prefetch next column group
            int nj = (cg + 1) * 64 + lane;
            nx1 = x1s[nj]; ny1 = y1s[nj]; nx2 = x2s[nj]; ny2 = y2s[nj];
            nc = clss[nj];
        }
        float car = ((cx2 - cx1) + 1.0f) * ((cy2 - cy1) + 1.0f);
        u64 bal[8];
#pragma unroll
        for (int k = 0; k < 8; ++k) {
            float ix1 = fmaxf(rx1[k], cx1);
            float iy1 = fmaxf(ry1[k], cy1);
            float ix2 = fminf(rx2[k], cx2);
            float iy2 = fminf(ry2[k], cy2);
            float iw = fmaxf((ix2 - ix1) + 1.0f, 0.0f);
            float ih = fmaxf((iy2 - iy1) + 1.0f, 0.0f);
            float inter = iw * ih;
            float denom = ((rar[k] + car) - inter) + 1e-16f;
            bool cond = ((double)inter > KMID * (double)denom) && (cc == rcl[k]);
            bal[k] = __ballot(cond);
        }
        u64 v = bal[0];
#pragma unroll
        for (int k = 1; k < 8; ++k) if (lane == k) v = bal[k];
        if (lane < 8) rm64[(size_t)(i0 + lane) * 32 + cg] = v;
        cx1 = nx1; cy1 = ny1; cx2 = nx2; cy2 = ny2; cc = nc;
    }
}

// ---------------- NMS scan copy helper ----------------
// Copy chunk cc into dst, TRANSPOSED [word][row], words 16*(cc>>1)..63 only
// (words < 8*cc never consumed -- R5/R6 proof). Lane layout: r = o>>2,
// q4 = o&3; each lane loads 4 consecutive uint4 = 64 B; 4 lanes = full
// 256-B row -> perfectly coalesced. Diagonal self-words scrubbed.
__device__ __forceinline__ void copy_chunk(const uint32* __restrict__ rm,
                                           uint32* __restrict__ dst,
                                           int cc, int ctid) {
    const uint32* src = rm + (size_t)cc * CH * NWORD;
    int q4min = cc >> 1;
    for (int o = ctid; o < 1024; o += 960) {
        int q4 = o & 3, r = o >> 2;
        if (q4 < q4min) continue;
        const uint4* s4 = (const uint4*)(src + (size_t)r * NWORD + q4 * 16);
        uint4 v0 = s4[0], v1 = s4[1], v2 = s4[2], v3 = s4[3];
        int gi = cc * CH + r;
        int sg = gi >> 5;                          // diagonal word index
        uint32 smsk = ~((2u << (gi & 31)) - 1u);
        uint32 wv[16] = {v0.x, v0.y, v0.z, v0.w, v1.x, v1.y, v1.z, v1.w,
                         v2.x, v2.y, v2.z, v2.w, v3.x, v3.y, v3.z, v3.w};
        int wbase = q4 * 16;
        uint32* dp = dst + r;
#pragma unroll
        for (int j = 0; j < 16; ++j) {
            uint32 x = wv[j];
            if (wbase + j == sg) x &= smsk;        // branchless cndmask
            dp[(wbase + j) * CHP] = x;
        }
    }
}

// ---------------- NMS stage 3: group-batched greedy scan ----------------
__global__ __launch_bounds__(1024) void scan_kernel(const uint32* __restrict__ rowmask,
                                                    const uint32* __restrict__ vwords,
                                                    float* __restrict__ keepf) {
    __shared__ uint32 buf[2][64 * CHP];   // 2 x 66,560 B
    int bt  = blockIdx.x;
    int tid = threadIdx.x;
    int wv  = tid >> 6;
    int l   = tid & 63;
    const uint32* rm = rowmask + (size_t)bt * TOPK * NWORD;

    uint32 supp = 0, keepw = 0;
    if (wv == 0) supp = ~vwords[bt * 64 + l];

    if (wv > 0) copy_chunk(rm, buf[0], 0, tid - 64);
    __syncthreads();

    for (int c = 0; c < NCHUNK; ++c) {
        if (wv > 0) {
            if (c + 1 < NCHUNK) copy_chunk(rm, buf[(c + 1) & 1], c + 1, tid - 64);
        } else {
            const uint32* bp = buf[c & 1];
            uint4 sq[8];
            {
                int g0 = c * GPC;
                const uint4* sp = (const uint4*)(bp + g0 * CHP);
#pragma unroll
                for (int q = 0; q < 8; ++q) sq[q] = sp[q];
            }
            for (int gl = 0; gl < GPC; ++gl) {
                int g = c * GPC + gl;
                uint4 rwq[8];
                const uint4* rp = (const uint4*)(bp + l * CHP + gl * 32);
#pragma unroll
                for (int q = 0; q < 8; ++q) rwq[q] = rp[q];
                uint32 cur = __builtin_amdgcn_readlane(supp, g);
#pragma unroll
                for (int q = 0; q < 8; ++q) {
                    uint32 s0 = sq[q].x, s1 = sq[q].y, s2 = sq[q].z, s3 = sq[q].w;
                    int k = q * 4;
                    cur |= s0 & ((((cur >> (k + 0)) & 1u)) - 1u);
                    cur |= s1 & ((((cur >> (k + 1)) & 1u)) - 1u);
                    cur |= s2 & ((((cur >> (k + 2)) & 1u)) - 1u);
                    cur |= s3 & ((((cur >> (k + 3)) & 1u)) - 1u);
                }
                uint32 keep = ~cur;
                if (l == g) keepw = keep;
                if (gl + 1 < GPC) {
                    const uint4* sp = (const uint4*)(bp + (g + 1) * CHP + (gl + 1) * 32);
#pragma unroll
                    for (int q = 0; q < 8; ++q) sq[q] = sp[q];
                }
                uint32 upd = 0;
#pragma unroll
                for (int q = 0; q < 8; ++q) {
                    int k = q * 4;
                    upd |= rwq[q].x & (uint32)(((int)(keep << (31 - (k + 0)))) >> 31);
                    upd |= rwq[q].y & (uint32)(((int)(keep << (31 - (k + 1)))) >> 31);
                    upd |= rwq[q].z & (uint32)(((int)(keep << (31 - (k + 2)))) >> 31);
                    upd |= rwq[q].w & (uint32)(((int)(keep << (31 - (k + 3)))) >> 31);
                }
                supp |= upd;
            }
        }
        __syncthreads();
    }

    if (wv == 0) {
#pragma unroll
        for (int k = 0; k < 32; ++k)
            keepf[bt * TOPK + l * 32 + k] = (float)((keepw >> k) & 1u);
    }
}

extern "C" void kernel_launch(void* const* d_in, const int* in_sizes, int n_in,
                              void* d_out, int out_size, void* d_ws, size_t ws_size,
                              hipStream_t stream) {
    const float* inp     = (const float*)d_in[0];
    const float* anchors = (const float*)d_in[1];
    float* out   = (float*)d_out;                        // [B, N, 25]
    float* topf  = out  + (size_t)B * NCAND * CATTR;     // [B, 2048] indices as float
    float* keepf = topf + (size_t)B * TOPK;              // [B, 2048] 0/1 as float

    // workspace layout
    float*  cws = (float*)d_ws;                          // [B, NCAND] conf
    float*  gx1 = cws + B * NCAND;
    float*  gy1 = gx1 + B * TOPK;
    float*  gx2 = gy1 + B * TOPK;
    float*  gy2 = gx2 + B * TOPK;
    float*  gar = gy2 + B * TOPK;
    uint32* gcv = (uint32*)(gar + B * TOPK);
    uint32* rowmask = gcv + B * TOPK;                    // 16*2048*64 u32 = 8 MiB
    uint32* vwords  = rowmask + (size_t)B * TOPK * NWORD;
    // sort scratch aliases onto rowmask (sort completes before build writes)
    u64* runs = (u64*)rowmask;                           // 1 MiB

    decode_kernel<<<(B * NCAND) / 256, 256, 0, stream>>>(inp, anchors, out, cws);
    sort1_kernel<<<B * 4, 256, 0, stream>>>(cws, runs);
    sort23_kernel<<<B, 256, 0, stream>>>(runs, out, topf, gx1, gy1, gx2, gy2, gar, gcv, vwords);
    build_kernel<<<dim3(16, B), 1024, 0, stream>>>(gx1, gy1, gx2, gy2, gar, gcv, rowmask);
    scan_kernel<<<B, 1024, 0, stream>>>(rowmask, vwords, keepf);
}

// Round 13
// 184.280 us; speedup vs baseline: 1.3964x; 1.0123x over previous
//
#include <hip/hip_runtime.h>

#pragma clang fp contract(off)

#define B 16
#define A 3
#define HGT 52
#define WID 52
#define HW 2704
#define NCAND 8112   // A*HW
#define CATTR 25
#define TOPK 2048
#define NWORD 64     // 64 u32 words x 32 bits = 2048 cols
#define CH 256       // rows per scan chunk
#define NCHUNK (TOPK / CH)   // 8
#define GPC (CH / 32)        // 8 groups per chunk
#define CHP 260      // padded chunk-row stride (words); %4==0 keeps b128 align
#define EPT 8        // sort: elements per thread

typedef unsigned int uint32;
typedef unsigned long long u64;

// ---------------- decode ----------------
__global__ __launch_bounds__(256) void decode_kernel(const float* __restrict__ inp,
                                                     const float* __restrict__ anchors,
                                                     float* __restrict__ out,
                                                     float* __restrict__ cws) {
    __shared__ float sm[256 * CATTR];   // 25.6 KiB, candidate-major == out order
    int tid = threadIdx.x;
    int t = blockIdx.x * 256 + tid;     // < B*NCAND (129792 = 507*256 exactly)
    int b  = t / NCAND;
    int n  = t - b * NCAND;
    int a  = n / HW;
    int hw = n - a * HW;
    int gy = hw / WID;
    int gx = hw - gy * WID;
    const float* ip = inp + ((size_t)(b * (A * CATTR) + a * CATTR)) * HW + hw;
    float* sp = sm + tid * CATTR;

    float p0 = ip[0 * HW], p1 = ip[1 * HW], p2 = ip[2 * HW], p3 = ip[3 * HW], p4 = ip[4 * HW];
    float sx = 1.0f / (1.0f + expf(-p0));
    float sy = 1.0f / (1.0f + expf(-p1));
    float bx = (sx + (float)gx) * 8.0f;   // stride = 8 exactly
    float by = (sy + (float)gy) * 8.0f;
    float bw = expf(p2) * anchors[a * 2 + 0];   // (anchor/8)*8 exact
    float bh = expf(p3) * anchors[a * 2 + 1];
    float cf = 1.0f / (1.0f + expf(-p4));
    sp[0] = bx; sp[1] = by; sp[2] = bw; sp[3] = bh; sp[4] = cf;
    cws[t] = cf;   // contiguous conf for the sort
#pragma unroll
    for (int c = 0; c < 20; ++c) {
        float v = ip[(5 + c) * HW];
        sp[5 + c] = 1.0f / (1.0f + expf(-v));
    }
    __syncthreads();
    const float4* sm4 = (const float4*)sm;
    float4* o4 = (float4*)(out + (size_t)blockIdx.x * 256 * CATTR);
#pragma unroll
    for (int k = 0; k < 6; ++k) o4[k * 256 + tid] = sm4[k * 256 + tid];
    if (tid < 64) o4[1536 + tid] = sm4[1536 + tid];
}

// ---------------- sort helpers ----------------
// key = (~(conf_bits|sign) << 32) | idx ; ascending == conf desc, idx asc.
__device__ __forceinline__ void cexd(u64& a, u64& b, bool up) {
    if ((a > b) == up) { u64 tmp = a; a = b; b = tmp; }
}

__device__ __forceinline__ u64 sel(u64 k, u64 o, bool kmin) {
    return kmin ? (k < o ? k : o) : (k > o ? k : o);
}

// bitonic merge of a 2048-element bitonic sequence to ascending order.
__device__ __forceinline__ void bitonic_merge_2048(u64 key[EPT], u64* mb, int t) {
    for (unsigned j = 1024; j >= 8; j >>= 1) {
        unsigned m = j >> 3;
        bool kmin = ((t & m) == 0);
        if (m >= 64) {
            __syncthreads();
#pragma unroll
            for (int e = 0; e < EPT; ++e) mb[e * 256 + t] = key[e];
            __syncthreads();
            int pt = t ^ (int)m;
#pragma unroll
            for (int e = 0; e < EPT; ++e) key[e] = sel(key[e], mb[e * 256 + pt], kmin);
        } else {
#pragma unroll
            for (int e = 0; e < EPT; ++e) {
                u64 o = __shfl_xor(key[e], (int)m);
                key[e] = sel(key[e], o, kmin);
            }
        }
    }
    cexd(key[0], key[4], true); cexd(key[1], key[5], true);
    cexd(key[2], key[6], true); cexd(key[3], key[7], true);
    cexd(key[0], key[2], true); cexd(key[1], key[3], true);
    cexd(key[4], key[6], true); cexd(key[5], key[7], true);
    cexd(key[0], key[1], true); cexd(key[2], key[3], true);
    cexd(key[4], key[5], true); cexd(key[6], key[7], true);
}

// ---------------- S1: sort each 2048-chunk ascending ----------------
__global__ __launch_bounds__(256) void sort1_kernel(const float* __restrict__ conf,
                                                    u64* __restrict__ runs) {
    __shared__ u64 mb[2048];   // 16 KiB SoA mailbox
    int blk = blockIdx.x;
    int b = blk >> 2, c = blk & 3;
    int t = threadIdx.x;
    int base = t * EPT;               // local 0..2047
    int gbase = c * 2048 + base;      // candidate index in batch
    const float* cp = conf + b * NCAND;

    u64 key[EPT];
    if (gbase + EPT <= NCAND) {
        const float4* cp4 = (const float4*)(cp + gbase);
        float4 c0 = cp4[0], c1 = cp4[1];
        float cf[EPT] = {c0.x, c0.y, c0.z, c0.w, c1.x, c1.y, c1.z, c1.w};
#pragma unroll
        for (int e = 0; e < EPT; ++e) {
            unsigned bits = __float_as_uint(cf[e]) | 0x80000000u;
            key[e] = ((u64)(~bits) << 32) | (unsigned)(gbase + e);
        }
    } else {
#pragma unroll
        for (int e = 0; e < EPT; ++e) {
            int idx = gbase + e;
            if (idx < NCAND) {
                unsigned bits = __float_as_uint(cp[idx]) | 0x80000000u;
                key[e] = ((u64)(~bits) << 32) | (unsigned)idx;
            } else key[e] = ~0ull;   // pad sorts last
        }
    }

    cexd(key[0], key[1], true); cexd(key[2], key[3], false);
    cexd(key[4], key[5], true); cexd(key[6], key[7], false);

    cexd(key[0], key[2], true);  cexd(key[1], key[3], true);
    cexd(key[4], key[6], false); cexd(key[5], key[7], false);
    cexd(key[0], key[1], true);  cexd(key[2], key[3], true);
    cexd(key[4], key[5], false); cexd(key[6], key[7], false);

    bool up8 = ((t & 1) == 0);
    cexd(key[0], key[4], up8); cexd(key[1], key[5], up8);
    cexd(key[2], key[6], up8); cexd(key[3], key[7], up8);
    cexd(key[0], key[2], up8); cexd(key[1], key[3], up8);
    cexd(key[4], key[6], up8); cexd(key[5], key[7], up8);
    cexd(key[0], key[1], up8); cexd(key[2], key[3], up8);
    cexd(key[4], key[5], up8); cexd(key[6], key[7], up8);

    for (unsigned k = 16; k <= 2048; k <<= 1) {
        bool up = (((unsigned)base & k) == 0);
        for (unsigned j = k >> 1; j >= 8; j >>= 1) {
            unsigned m = j >> 3;
            bool kmin = (up == ((t & m) == 0));
            if (m >= 64) {
                __syncthreads();
#pragma unroll
                for (int e = 0; e < EPT; ++e) mb[e * 256 + t] = key[e];
                __syncthreads();
                int pt = t ^ (int)m;
#pragma unroll
                for (int e = 0; e < EPT; ++e) key[e] = sel(key[e], mb[e * 256 + pt], kmin);
            } else {
#pragma unroll
                for (int e = 0; e < EPT; ++e) {
                    u64 o = __shfl_xor(key[e], (int)m);
                    key[e] = sel(key[e], o, kmin);
                }
            }
        }
        cexd(key[0], key[4], up); cexd(key[1], key[5], up);
        cexd(key[2], key[6], up); cexd(key[3], key[7], up);
        cexd(key[0], key[2], up); cexd(key[1], key[3], up);
        cexd(key[4], key[6], up); cexd(key[5], key[7], up);
        cexd(key[0], key[1], up); cexd(key[2], key[3], up);
        cexd(key[4], key[5], up); cexd(key[6], key[7], up);
    }

    u64* R = runs + ((size_t)b * 4 + c) * 2048;
#pragma unroll
    for (int e = 0; e < EPT; ++e) R[base + e] = key[e];
}

// ---------------- S23: fused 4-run prune-merge tree -> topf + geometry ----
__global__ __launch_bounds__(256) void sort23_kernel(const u64* __restrict__ runs,
                                                     const float* __restrict__ out,
                                                     float* __restrict__ topf,
                                                     float* __restrict__ gx1,
                                                     float* __restrict__ gy1,
                                                     float* __restrict__ gx2,
                                                     float* __restrict__ gy2,
                                                     float* __restrict__ gar,
                                                     uint32* __restrict__ gcv,
                                                     uint32* __restrict__ vwords) {
    __shared__ u64 mb[2048];
    __shared__ uint32 vb[256];
    int b = blockIdx.x;
    int t = threadIdx.x;
    int base = t * EPT;
    const u64* R0 = runs + (size_t)b * 4 * 2048;

    u64 ka[EPT], kb[EPT];
#pragma unroll
    for (int e = 0; e < EPT; ++e) {
        u64 a = R0[base + e];
        u64 o = R0[2048 + 2047 - (base + e)];
        ka[e] = a < o ? a : o;
    }
    bitonic_merge_2048(ka, mb, t);
#pragma unroll
    for (int e = 0; e < EPT; ++e) {
        u64 a = R0[2 * 2048 + base + e];
        u64 o = R0[3 * 2048 + 2047 - (base + e)];
        kb[e] = a < o ? a : o;
    }
    bitonic_merge_2048(kb, mb, t);
    __syncthreads();
#pragma unroll
    for (int e = 0; e < EPT; ++e) mb[base + e] = kb[e];
    __syncthreads();
#pragma unroll
    for (int e = 0; e < EPT; ++e) {
        u64 o = mb[2047 - (base + e)];
        ka[e] = ka[e] < o ? ka[e] : o;
    }
    bitonic_merge_2048(ka, mb, t);

    const float* ob = out + (size_t)b * NCAND * CATTR;
    uint32 vbits = 0;
#pragma unroll
    for (int e = 0; e < EPT; ++e) {
        uint32 idx = (uint32)(ka[e] & 0xFFFFFFFFu);
        int tg = b * TOPK + base + e;
        topf[tg] = (float)idx;
        const float* p = ob + (size_t)idx * CATTR;
        float cx = p[0], cy = p[1], w = p[2], h = p[3], cf = p[4];
        float hw_ = w * 0.5f, hh_ = h * 0.5f;  // w/2 exact
        float x1 = cx - hw_, y1 = cy - hh_, x2 = cx + hw_, y2 = cy + hh_;
        gx1[tg] = x1; gy1[tg] = y1; gx2[tg] = x2; gy2[tg] = y2;
        gar[tg] = ((x2 - x1) + 1.0f) * ((y2 - y1) + 1.0f);
        float best = p[5]; int bc = 0;
#pragma unroll
        for (int c = 1; c < 20; ++c) {      // first-max argmax (numpy semantics)
            float v = p[5 + c];
            if (v > best) { best = v; bc = c; }
        }
        gcv[tg] = (uint32)bc;
        vbits |= (cf >= 0.5f ? 1u : 0u) << e;
    }
    vb[t] = vbits;
    __syncthreads();
    if (t < 64) {
        uint32 w4 = vb[t * 4] | (vb[t * 4 + 1] << 8) | (vb[t * 4 + 2] << 16) | (vb[t * 4 + 3] << 24);
        vwords[b * 64 + t] = w4;
    }
}

// ---------------- NMS stage 2: suppression bitmask build (TRANSPOSED) -----
// Output layout: rmT[word][row] per batch (64 x 2048 u32). Strict upper
// triangle only; diagonal self-words scrubbed here (bits <= row%32 cleared)
// so the scan's resolve chain is monotone. Sub-diagonal words unwritten /
// garbage: provably never consumed (R5/R6/R12 proof).
// Exact div-free IoU threshold (R5 proof).
#define KMID (13421772.5 / 33554432.0)
__global__ __launch_bounds__(1024) void build_kernel(const float* __restrict__ gx1,
                                                     const float* __restrict__ gy1,
                                                     const float* __restrict__ gx2,
                                                     const float* __restrict__ gy2,
                                                     const float* __restrict__ gar,
                                                     const uint32* __restrict__ gcv,
                                                     uint32* __restrict__ rowmask) {
    __shared__ float  x1s[TOPK], y1s[TOPK], x2s[TOPK], y2s[TOPK];  // 32 KiB
    __shared__ uint32 clss[TOPK];                                  // 8 KiB
    int bt   = blockIdx.y;
    int pr   = blockIdx.x;          // pair 0..15
    int tid  = threadIdx.x;
    int lane = tid & 63;
    int wv   = tid >> 6;            // wave 0..15
    int base = bt * TOPK;
    uint32* rmT = rowmask + (size_t)base * NWORD;   // [word][2048]

    for (int j = tid; j < TOPK; j += 1024) {
        int g = base + j;
        x1s[j] = gx1[g]; y1s[j] = gy1[g]; x2s[j] = gx2[g]; y2s[j] = gy2[g];
        clss[j] = gcv[g] & 0xffu;
    }
    __syncthreads();

    int r  = (wv >> 3) ? (31 - pr) : pr;   // strip index
    int i0 = r * 64 + (wv & 7) * 8;        // this wave's 8 rows

    float rx1[8], ry1[8], rx2[8], ry2[8], rar[8];
    uint32 rcl[8];
#pragma unroll
    for (int k = 0; k < 8; ++k) {
        rx1[k] = x1s[i0 + k]; ry1[k] = y1s[i0 + k];
        rx2[k] = x2s[i0 + k]; ry2[k] = y2s[i0 + k];
        rar[k] = ((rx2[k] - rx1[k]) + 1.0f) * ((ry2[k] - ry1[k]) + 1.0f);
        rcl[k] = clss[i0 + k];
    }

    int j0 = r * 64 + lane;
    float cx1 = x1s[j0], cy1 = y1s[j0], cx2 = x2s[j0], cy2 = y2s[j0];
    uint32 cc = clss[j0];

    for (int cg = r; cg < 32; ++cg) {
        float nx1 = 0.f, ny1 = 0.f, nx2 = 0.f, ny2 = 0.f; uint32 nc = 0;
        if (cg + 1 < 32) {      // prefetch next column group
            int nj = (cg + 1) * 64 + lane;
            nx1 = x1s[nj]; ny1 = y1s[nj]; nx2 = x2s[nj]; ny2 = y2s[nj];
            nc = clss[nj];
        }
        float car = ((cx2 - cx1) + 1.0f) * ((cy2 - cy1) + 1.0f);
        u64 bal[8];
#pragma unroll
        for (int k = 0; k < 8; ++k) {
            float ix1 = fmaxf(rx1[k], cx1);
            float iy1 = fmaxf(ry1[k], cy1);
            float ix2 = fminf(rx2[k], cx2);
            float iy2 = fminf(ry2[k], cy2);
            float iw = fmaxf((ix2 - ix1) + 1.0f, 0.0f);
            float ih = fmaxf((iy2 - iy1) + 1.0f, 0.0f);
            float inter = iw * ih;
            float denom = ((rar[k] + car) - inter) + 1e-16f;
            bool cond = ((double)inter > KMID * (double)denom) && (cc == rcl[k]);
            bal[k] = __ballot(cond);
        }
        // pack: lanes 0..7 -> low words, lanes 8..15 -> high words of rows i0..i0+7
        u64 v = bal[0];
#pragma unroll
        for (int k = 1; k < 8; ++k) if ((lane & 7) == k) v = bal[k];
        uint32 w32 = (lane & 8) ? (uint32)(v >> 32) : (uint32)v;
        int gi = i0 + (lane & 7);
        int wd = 2 * cg + ((lane >> 3) & 1);
        if (wd == (gi >> 5)) w32 &= ~((2u << (gi & 31)) - 1u);   // diagonal scrub
        if (lane < 16) rmT[(size_t)wd * TOPK + gi] = w32;
        cx1 = nx1; cy1 = ny1; cx2 = nx2; cy2 = ny2; cc = nc;
    }
}

// ---------------- NMS scan copy: global_load_lds DMA ----------------
// rmT is [word][row]. For chunk c, word w covers rows c*256..+255 -> ONE
// global_load_lds dwordx4 per word: lane i reads 16 B (rows c*256+4i..+3),
// LDS dst = uniform base buf + w*CHP, lane x 16 B appended -> exactly
// buf[w*CHP + r]. Pad legal (base uniform). Trim w >= 8c (dead below).
__device__ __forceinline__ void copy_chunk_dma(const uint32* __restrict__ rmT,
                                               uint32* dstL, int c, int wvm1, int lane) {
    int wmin = 8 * c;
    for (int w = wmin + wvm1; w < 64; w += 15) {
        const uint32* gp = rmT + (size_t)w * TOPK + c * CH + lane * 4;
        uint32* lp = dstL + w * CHP;
        __builtin_amdgcn_global_load_lds((const __attribute__((address_space(1))) void*)gp,
                                         (__attribute__((address_space(3))) void*)lp,
                                         16, 0, 0);
    }
}

// ---------------- NMS stage 3: group-batched greedy scan ----------------
// Wave 0 scans; waves 1-15 DMA chunks into double-buffered LDS. Resolve:
// 8x broadcast b128 self-words (scrubbed in build -> monotone chain),
// keep = ~cur, masked OR of all 32 rows (8x b128/lane). Stale/garbage
// words at l < g provably never consumed.
__global__ __launch_bounds__(1024) void scan_kernel(const uint32* __restrict__ rowmask,
                                                    const uint32* __restrict__ vwords,
                                                    float* __restrict__ keepf) {
    __shared__ uint32 buf[2][64 * CHP];   // 2 x 66,560 B
    int bt  = blockIdx.x;
    int tid = threadIdx.x;
    int wv  = tid >> 6;
    int l   = tid & 63;
    const uint32* rmT = rowmask + (size_t)bt * TOPK * NWORD;

    uint32 supp = 0, keepw = 0;
    if (wv == 0) supp = ~vwords[bt * 64 + l];

    if (wv > 0) copy_chunk_dma(rmT, buf[0], 0, wv - 1, l);
    __syncthreads();

    for (int c = 0; c < NCHUNK; ++c) {
        if (wv > 0) {
            if (c + 1 < NCHUNK) copy_chunk_dma(rmT, buf[(c + 1) & 1], c + 1, wv - 1, l);
        } else {
            const uint32* bp = buf[c & 1];
            uint4 sq[8];
            {
                int g0 = c * GPC;
                const uint4* sp = (const uint4*)(bp + g0 * CHP);
#pragma unroll
                for (int q = 0; q < 8; ++q) sq[q] = sp[q];
            }
            for (int gl = 0; gl < GPC; ++gl) {
                int g = c * GPC + gl;
                uint4 rwq[8];
                const uint4* rp = (const uint4*)(bp + l * CHP + gl * 32);
#pragma unroll
                for (int q = 0; q < 8; ++q) rwq[q] = rp[q];
                uint32 cur = __builtin_amdgcn_readlane(supp, g);
#pragma unroll
                for (int q = 0; q < 8; ++q) {
                    uint32 s0 = sq[q].x, s1 = sq[q].y, s2 = sq[q].z, s3 = sq[q].w;
                    int k = q * 4;
                    cur |= s0 & ((((cur >> (k + 0)) & 1u)) - 1u);
                    cur |= s1 & ((((cur >> (k + 1)) & 1u)) - 1u);
                    cur |= s2 & ((((cur >> (k + 2)) & 1u)) - 1u);
                    cur |= s3 & ((((cur >> (k + 3)) & 1u)) - 1u);
                }
                uint32 keep = ~cur;
                if (l == g) keepw = keep;
                if (gl + 1 < GPC) {
                    const uint4* sp = (const uint4*)(bp + (g + 1) * CHP + (gl + 1) * 32);
#pragma unroll
                    for (int q = 0; q < 8; ++q) sq[q] = sp[q];
                }
                uint32 upd = 0;
#pragma unroll
                for (int q = 0; q < 8; ++q) {
                    int k = q * 4;
                    upd |= rwq[q].x & (uint32)(((int)(keep << (31 - (k + 0)))) >> 31);
                    upd |= rwq[q].y & (uint32)(((int)(keep << (31 - (k + 1)))) >> 31);
                    upd |= rwq[q].z & (uint32)(((int)(keep << (31 - (k + 2)))) >> 31);
                    upd |= rwq[q].w & (uint32)(((int)(keep << (31 - (k + 3)))) >> 31);
                }
                supp |= upd;
            }
        }
        __syncthreads();
    }

    if (wv == 0) {
#pragma unroll
        for (int k = 0; k < 32; ++k)
            keepf[bt * TOPK + l * 32 + k] = (float)((keepw >> k) & 1u);
    }
}

extern "C" void kernel_launch(void* const* d_in, const int* in_sizes, int n_in,
                              void* d_out, int out_size, void* d_ws, size_t ws_size,
                              hipStream_t stream) {
    const float* inp     = (const float*)d_in[0];
    const float* anchors = (const float*)d_in[1];
    float* out   = (float*)d_out;                        // [B, N, 25]
    float* topf  = out  + (size_t)B * NCAND * CATTR;     // [B, 2048] indices as float
    float* keepf = topf + (size_t)B * TOPK;              // [B, 2048] 0/1 as float

    // workspace layout
    float*  cws = (float*)d_ws;                          // [B, NCAND] conf
    float*  gx1 = cws + B * NCAND;
    float*  gy1 = gx1 + B * TOPK;
    float*  gx2 = gy1 + B * TOPK;
    float*  gy2 = gx2 + B * TOPK;
    float*  gar = gy2 + B * TOPK;
    uint32* gcv = (uint32*)(gar + B * TOPK);
    uint32* rowmask = gcv + B * TOPK;                    // rmT: [B][64][2048] u32 = 8 MiB
    uint32* vwords  = rowmask + (size_t)B * TOPK * NWORD;
    // sort scratch aliases onto rowmask (sort completes before build writes)
    u64* runs = (u64*)rowmask;                           // 1 MiB

    decode_kernel<<<(B * NCAND) / 256, 256, 0, stream>>>(inp, anchors, out, cws);
    sort1_kernel<<<B * 4, 256, 0, stream>>>(cws, runs);
    sort23_kernel<<<B, 256, 0, stream>>>(runs, out, topf, gx1, gy1, gx2, gy2, gar, gcv, vwords);
    build_kernel<<<dim3(16, B), 1024, 0, stream>>>(gx1, gy1, gx2, gy2, gar, gcv, rowmask);
    scan_kernel<<<B, 1024, 0, stream>>>(rowmask, vwords, keepf);
}

// Round 14
// 175.264 us; speedup vs baseline: 1.4683x; 1.0514x over previous
//
#include <hip/hip_runtime.h>

#pragma clang fp contract(off)

#define B 16
#define A 3
#define HGT 52
#define WID 52
#define HW 2704
#define NCAND 8112   // A*HW
#define CATTR 25
#define TOPK 2048
#define NWORD 64     // 64 u32 words x 32 bits = 2048 cols
#define CH 256       // rows per scan chunk
#define NCHUNK (TOPK / CH)   // 8
#define GPC (CH / 32)        // 8 groups per chunk
#define CHP 260      // padded chunk-row stride (words); %4==0 keeps b128 align
#define EPT 8        // sort: elements per thread

typedef unsigned int uint32;
typedef unsigned long long u64;

// ---------------- decode ----------------
// Writes out[b,n,25] (via LDS transpose, coalesced) + conf for the sort +
// a packed 8-float geometry record pk[b,n,8] = {x1,y1,x2,y2, area, cls,
// valid, 0} so the post-topk gather reads 32 B instead of 100 B.
// All f32 ops in the same order as the reference -> bit-identical.
__global__ __launch_bounds__(256) void decode_kernel(const float* __restrict__ inp,
                                                     const float* __restrict__ anchors,
                                                     float* __restrict__ out,
                                                     float* __restrict__ cws,
                                                     float* __restrict__ pk) {
    __shared__ float sm[256 * CATTR];   // 25.6 KiB, candidate-major == out order
    int tid = threadIdx.x;
    int t = blockIdx.x * 256 + tid;     // < B*NCAND (129792 = 507*256 exactly)
    int b  = t / NCAND;
    int n  = t - b * NCAND;
    int a  = n / HW;
    int hw = n - a * HW;
    int gy = hw / WID;
    int gx = hw - gy * WID;
    const float* ip = inp + ((size_t)(b * (A * CATTR) + a * CATTR)) * HW + hw;
    float* sp = sm + tid * CATTR;

    float p0 = ip[0 * HW], p1 = ip[1 * HW], p2 = ip[2 * HW], p3 = ip[3 * HW], p4 = ip[4 * HW];
    float sx = 1.0f / (1.0f + expf(-p0));
    float sy = 1.0f / (1.0f + expf(-p1));
    float bx = (sx + (float)gx) * 8.0f;   // stride = 8 exactly
    float by = (sy + (float)gy) * 8.0f;
    float bw = expf(p2) * anchors[a * 2 + 0];   // (anchor/8)*8 exact
    float bh = expf(p3) * anchors[a * 2 + 1];
    float cf = 1.0f / (1.0f + expf(-p4));
    sp[0] = bx; sp[1] = by; sp[2] = bw; sp[3] = bh; sp[4] = cf;
    cws[t] = cf;   // contiguous conf for the sort

    float best = -1.0f; int bc = 0;
#pragma unroll
    for (int c = 0; c < 20; ++c) {
        float v = ip[(5 + c) * HW];
        float s = 1.0f / (1.0f + expf(-v));
        sp[5 + c] = s;
        if (s > best) { best = s; bc = c; }   // first-max (numpy semantics;
    }                                         // sigmoid>0 so c=0 always sets)

    // packed geometry record (same op order as old geo: w*0.5f exact)
    float hw_ = bw * 0.5f, hh_ = bh * 0.5f;
    float x1 = bx - hw_, y1 = by - hh_, x2 = bx + hw_, y2 = by + hh_;
    float area = ((x2 - x1) + 1.0f) * ((y2 - y1) + 1.0f);
    float4* pk4 = (float4*)(pk + (size_t)t * 8);
    pk4[0] = make_float4(x1, y1, x2, y2);
    pk4[1] = make_float4(area, (float)bc, (cf >= 0.5f) ? 1.0f : 0.0f, 0.0f);

    __syncthreads();
    const float4* sm4 = (const float4*)sm;
    float4* o4 = (float4*)(out + (size_t)blockIdx.x * 256 * CATTR);
#pragma unroll
    for (int k = 0; k < 6; ++k) o4[k * 256 + tid] = sm4[k * 256 + tid];
    if (tid < 64) o4[1536 + tid] = sm4[1536 + tid];
}

// ---------------- sort helpers ----------------
// key = (~(conf_bits|sign) << 32) | idx ; ascending == conf desc, idx asc.
__device__ __forceinline__ void cexd(u64& a, u64& b, bool up) {
    if ((a > b) == up) { u64 tmp = a; a = b; b = tmp; }
}

__device__ __forceinline__ u64 sel(u64 k, u64 o, bool kmin) {
    return kmin ? (k < o ? k : o) : (k > o ? k : o);
}

// bitonic merge of a 2048-element bitonic sequence to ascending order.
__device__ __forceinline__ void bitonic_merge_2048(u64 key[EPT], u64* mb, int t) {
    for (unsigned j = 1024; j >= 8; j >>= 1) {
        unsigned m = j >> 3;
        bool kmin = ((t & m) == 0);
        if (m >= 64) {
            __syncthreads();
#pragma unroll
            for (int e = 0; e < EPT; ++e) mb[e * 256 + t] = key[e];
            __syncthreads();
            int pt = t ^ (int)m;
#pragma unroll
            for (int e = 0; e < EPT; ++e) key[e] = sel(key[e], mb[e * 256 + pt], kmin);
        } else {
#pragma unroll
            for (int e = 0; e < EPT; ++e) {
                u64 o = __shfl_xor(key[e], (int)m);
                key[e] = sel(key[e], o, kmin);
            }
        }
    }
    cexd(key[0], key[4], true); cexd(key[1], key[5], true);
    cexd(key[2], key[6], true); cexd(key[3], key[7], true);
    cexd(key[0], key[2], true); cexd(key[1], key[3], true);
    cexd(key[4], key[6], true); cexd(key[5], key[7], true);
    cexd(key[0], key[1], true); cexd(key[2], key[3], true);
    cexd(key[4], key[5], true); cexd(key[6], key[7], true);
}

// ---------------- S1: sort each 2048-chunk ascending ----------------
__global__ __launch_bounds__(256) void sort1_kernel(const float* __restrict__ conf,
                                                    u64* __restrict__ runs) {
    __shared__ u64 mb[2048];   // 16 KiB SoA mailbox
    int blk = blockIdx.x;
    int b = blk >> 2, c = blk & 3;
    int t = threadIdx.x;
    int base = t * EPT;               // local 0..2047
    int gbase = c * 2048 + base;      // candidate index in batch
    const float* cp = conf + b * NCAND;

    u64 key[EPT];
    if (gbase + EPT <= NCAND) {
        const float4* cp4 = (const float4*)(cp + gbase);
        float4 c0 = cp4[0], c1 = cp4[1];
        float cf[EPT] = {c0.x, c0.y, c0.z, c0.w, c1.x, c1.y, c1.z, c1.w};
#pragma unroll
        for (int e = 0; e < EPT; ++e) {
            unsigned bits = __float_as_uint(cf[e]) | 0x80000000u;
            key[e] = ((u64)(~bits) << 32) | (unsigned)(gbase + e);
        }
    } else {
#pragma unroll
        for (int e = 0; e < EPT; ++e) {
            int idx = gbase + e;
            if (idx < NCAND) {
                unsigned bits = __float_as_uint(cp[idx]) | 0x80000000u;
                key[e] = ((u64)(~bits) << 32) | (unsigned)idx;
            } else key[e] = ~0ull;   // pad sorts last
        }
    }

    cexd(key[0], key[1], true); cexd(key[2], key[3], false);
    cexd(key[4], key[5], true); cexd(key[6], key[7], false);

    cexd(key[0], key[2], true);  cexd(key[1], key[3], true);
    cexd(key[4], key[6], false); cexd(key[5], key[7], false);
    cexd(key[0], key[1], true);  cexd(key[2], key[3], true);
    cexd(key[4], key[5], false); cexd(key[6], key[7], false);

    bool up8 = ((t & 1) == 0);
    cexd(key[0], key[4], up8); cexd(key[1], key[5], up8);
    cexd(key[2], key[6], up8); cexd(key[3], key[7], up8);
    cexd(key[0], key[2], up8); cexd(key[1], key[3], up8);
    cexd(key[4], key[6], up8); cexd(key[5], key[7], up8);
    cexd(key[0], key[1], up8); cexd(key[2], key[3], up8);
    cexd(key[4], key[5], up8); cexd(key[6], key[7], up8);

    for (unsigned k = 16; k <= 2048; k <<= 1) {
        bool up = (((unsigned)base & k) == 0);
        for (unsigned j = k >> 1; j >= 8; j >>= 1) {
            unsigned m = j >> 3;
            bool kmin = (up == ((t & m) == 0));
            if (m >= 64) {
                __syncthreads();
#pragma unroll
                for (int e = 0; e < EPT; ++e) mb[e * 256 + t] = key[e];
                __syncthreads();
                int pt = t ^ (int)m;
#pragma unroll
                for (int e = 0; e < EPT; ++e) key[e] = sel(key[e], mb[e * 256 + pt], kmin);
            } else {
#pragma unroll
                for (int e = 0; e < EPT; ++e) {
                    u64 o = __shfl_xor(key[e], (int)m);
                    key[e] = sel(key[e], o, kmin);
                }
            }
        }
        cexd(key[0], key[4], up); cexd(key[1], key[5], up);
        cexd(key[2], key[6], up); cexd(key[3], key[7], up);
        cexd(key[0], key[2], up); cexd(key[1], key[3], up);
        cexd(key[4], key[6], up); cexd(key[5], key[7], up);
        cexd(key[0], key[1], up); cexd(key[2], key[3], up);
        cexd(key[4], key[5], up); cexd(key[6], key[7], up);
    }

    u64* R = runs + ((size_t)b * 4 + c) * 2048;
#pragma unroll
    for (int e = 0; e < EPT; ++e) R[base + e] = key[e];
}

// ---------------- S23: fused 4-run prune-merge tree -> topf only ---------
// (gather tail removed -- it was latency-bound at 16-block occupancy; the
//  standalone geo_kernel below does it at 128-block parallelism)
__global__ __launch_bounds__(256) void sort23_kernel(const u64* __restrict__ runs,
                                                     float* __restrict__ topf) {
    __shared__ u64 mb[2048];
    int b = blockIdx.x;
    int t = threadIdx.x;
    int base = t * EPT;
    const u64* R0 = runs + (size_t)b * 4 * 2048;

    u64 ka[EPT], kb[EPT];
#pragma unroll
    for (int e = 0; e < EPT; ++e) {
        u64 a = R0[base + e];
        u64 o = R0[2048 + 2047 - (base + e)];
        ka[e] = a < o ? a : o;
    }
    bitonic_merge_2048(ka, mb, t);
#pragma unroll
    for (int e = 0; e < EPT; ++e) {
        u64 a = R0[2 * 2048 + base + e];
        u64 o = R0[3 * 2048 + 2047 - (base + e)];
        kb[e] = a < o ? a : o;
    }
    bitonic_merge_2048(kb, mb, t);
    __syncthreads();
#pragma unroll
    for (int e = 0; e < EPT; ++e) mb[base + e] = kb[e];
    __syncthreads();
#pragma unroll
    for (int e = 0; e < EPT; ++e) {
        u64 o = mb[2047 - (base + e)];
        ka[e] = ka[e] < o ? ka[e] : o;
    }
    bitonic_merge_2048(ka, mb, t);

#pragma unroll
    for (int e = 0; e < EPT; ++e)
        topf[(size_t)b * TOPK + base + e] = (float)(unsigned)(ka[e] & 0xFFFFFFFFu);
}

// ---------------- geo: packed gather by topf ----------------
// grid = B*TOPK/256 = 128 blocks. 2x float4 per candidate from pk.
__global__ __launch_bounds__(256) void geo_kernel(const float* __restrict__ pk,
                                                  const float* __restrict__ topf,
                                                  float* __restrict__ gx1,
                                                  float* __restrict__ gy1,
                                                  float* __restrict__ gx2,
                                                  float* __restrict__ gy2,
                                                  float* __restrict__ gar,
                                                  uint32* __restrict__ gcv,
                                                  uint32* __restrict__ vwords) {
    int t = blockIdx.x * 256 + threadIdx.x;   // < B*TOPK
    int b = t >> 11;
    int idx = (int)topf[t];
    const float4* p4 = (const float4*)(pk + ((size_t)b * NCAND + idx) * 8);
    float4 g0 = p4[0], g1 = p4[1];
    gx1[t] = g0.x; gy1[t] = g0.y; gx2[t] = g0.z; gy2[t] = g0.w;
    gar[t] = g1.x;
    gcv[t] = (uint32)g1.y;
    bool valid = (g1.z != 0.0f);
    unsigned long long bal = __ballot(valid);   // t wave-aligned
    if ((t & 63) == 0) {
        vwords[(t >> 5) + 0] = (uint32)bal;
        vwords[(t >> 5) + 1] = (uint32)(bal >> 32);
    }
}

// ---------------- NMS stage 2: suppression bitmask build (TRANSPOSED) -----
// rmT[word][row] per batch. Strict upper triangle; diagonal scrubbed here.
// Exact div-free IoU threshold (R5 proof).
#define KMID (13421772.5 / 33554432.0)
__global__ __launch_bounds__(1024) void build_kernel(const float* __restrict__ gx1,
                                                     const float* __restrict__ gy1,
                                                     const float* __restrict__ gx2,
                                                     const float* __restrict__ gy2,
                                                     const float* __restrict__ gar,
                                                     const uint32* __restrict__ gcv,
                                                     uint32* __restrict__ rowmask) {
    __shared__ float  x1s[TOPK], y1s[TOPK], x2s[TOPK], y2s[TOPK];  // 32 KiB
    __shared__ uint32 clss[TOPK];                                  // 8 KiB
    int bt   = blockIdx.y;
    int pr   = blockIdx.x;          // pair 0..15
    int tid  = threadIdx.x;
    int lane = tid & 63;
    int wv   = tid >> 6;            // wave 0..15
    int base = bt * TOPK;
    uint32* rmT = rowmask + (size_t)base * NWORD;   // [word][2048]

    for (int j = tid; j < TOPK; j += 1024) {
        int g = base + j;
        x1s[j] = gx1[g]; y1s[j] = gy1[g]; x2s[j] = gx2[g]; y2s[j] = gy2[g];
        clss[j] = gcv[g] & 0xffu;
    }
    __syncthreads();

    int r  = (wv >> 3) ? (31 - pr) : pr;   // strip index
    int i0 = r * 64 + (wv & 7) * 8;        // this wave's 8 rows

    float rx1[8], ry1[8], rx2[8], ry2[8], rar[8];
    uint32 rcl[8];
#pragma unroll
    for (int k = 0; k < 8; ++k) {
        rx1[k] = x1s[i0 + k]; ry1[k] = y1s[i0 + k];
        rx2[k] = x2s[i0 + k]; ry2[k] = y2s[i0 + k];
        rar[k] = ((rx2[k] - rx1[k]) + 1.0f) * ((ry2[k] - ry1[k]) + 1.0f);
        rcl[k] = clss[i0 + k];
    }

    int j0 = r * 64 + lane;
    float cx1 = x1s[j0], cy1 = y1s[j0], cx2 = x2s[j0], cy2 = y2s[j0];
    uint32 cc = clss[j0];

    for (int cg = r; cg < 32; ++cg) {
        float nx1 = 0.f, ny1 = 0.f, nx2 = 0.f, ny2 = 0.f; uint32 nc = 0;
        if (cg + 1 < 32) {      // prefetch next column group
            int nj = (cg + 1) * 64 + lane;
            nx1 = x1s[nj]; ny1 = y1s[nj]; nx2 = x2s[nj]; ny2 = y2s[nj];
            nc = clss[nj];
        }
        float car = ((cx2 - cx1) + 1.0f) * ((cy2 - cy1) + 1.0f);
        u64 bal[8];
#pragma unroll
        for (int k = 0; k < 8; ++k) {
            float ix1 = fmaxf(rx1[k], cx1);
            float iy1 = fmaxf(ry1[k], cy1);
            float ix2 = fminf(rx2[k], cx2);
            float iy2 = fminf(ry2[k], cy2);
            float iw = fmaxf((ix2 - ix1) + 1.0f, 0.0f);
            float ih = fmaxf((iy2 - iy1) + 1.0f, 0.0f);
            float inter = iw * ih;
            float denom = ((rar[k] + car) - inter) + 1e-16f;
            bool cond = ((double)inter > KMID * (double)denom) && (cc == rcl[k]);
            bal[k] = __ballot(cond);
        }
        // pack: lanes 0..7 -> low words, lanes 8..15 -> high words of rows i0..i0+7
        u64 v = bal[0];
#pragma unroll
        for (int k = 1; k < 8; ++k) if ((lane & 7) == k) v = bal[k];
        uint32 w32 = (lane & 8) ? (uint32)(v >> 32) : (uint32)v;
        int gi = i0 + (lane & 7);
        int wd = 2 * cg + ((lane >> 3) & 1);
        if (wd == (gi >> 5)) w32 &= ~((2u << (gi & 31)) - 1u);   // diagonal scrub
        if (lane < 16) rmT[(size_t)wd * TOPK + gi] = w32;
        cx1 = nx1; cy1 = ny1; cx2 = nx2; cy2 = ny2; cc = nc;
    }
}

// ---------------- NMS scan copy: global_load_lds DMA ----------------
// rmT is [word][row]. For chunk c, word w covers rows c*256..+255 -> ONE
// global_load_lds dwordx4 per word. Trim w >= 8c (dead below).
__device__ __forceinline__ void copy_chunk_dma(const uint32* __restrict__ rmT,
                                               uint32* dstL, int c, int wvm1, int lane) {
    int wmin = 8 * c;
    for (int w = wmin + wvm1; w < 64; w += 15) {
        const uint32* gp = rmT + (size_t)w * TOPK + c * CH + lane * 4;
        uint32* lp = dstL + w * CHP;
        __builtin_amdgcn_global_load_lds((const __attribute__((address_space(1))) void*)gp,
                                         (__attribute__((address_space(3))) void*)lp,
                                         16, 0, 0);
    }
}

// ---------------- NMS stage 3: group-batched greedy scan ----------------
__global__ __launch_bounds__(1024) void scan_kernel(const uint32* __restrict__ rowmask,
                                                    const uint32* __restrict__ vwords,
                                                    float* __restrict__ keepf) {
    __shared__ uint32 buf[2][64 * CHP];   // 2 x 66,560 B
    int bt  = blockIdx.x;
    int tid = threadIdx.x;
    int wv  = tid >> 6;
    int l   = tid & 63;
    const uint32* rmT = rowmask + (size_t)bt * TOPK * NWORD;

    uint32 supp = 0, keepw = 0;
    if (wv == 0) supp = ~vwords[bt * 64 + l];

    if (wv > 0) copy_chunk_dma(rmT, buf[0], 0, wv - 1, l);
    __syncthreads();

    for (int c = 0; c < NCHUNK; ++c) {
        if (wv > 0) {
            if (c + 1 < NCHUNK) copy_chunk_dma(rmT, buf[(c + 1) & 1], c + 1, wv - 1, l);
        } else {
            const uint32* bp = buf[c & 1];
            uint4 sq[8];
            {
                int g0 = c * GPC;
                const uint4* sp = (const uint4*)(bp + g0 * CHP);
#pragma unroll
                for (int q = 0; q < 8; ++q) sq[q] = sp[q];
            }
            for (int gl = 0; gl < GPC; ++gl) {
                int g = c * GPC + gl;
                uint4 rwq[8];
                const uint4* rp = (const uint4*)(bp + l * CHP + gl * 32);
#pragma unroll
                for (int q = 0; q < 8; ++q) rwq[q] = rp[q];
                uint32 cur = __builtin_amdgcn_readlane(supp, g);
#pragma unroll
                for (int q = 0; q < 8; ++q) {
                    uint32 s0 = sq[q].x, s1 = sq[q].y, s2 = sq[q].z, s3 = sq[q].w;
                    int k = q * 4;
                    cur |= s0 & ((((cur >> (k + 0)) & 1u)) - 1u);
                    cur |= s1 & ((((cur >> (k + 1)) & 1u)) - 1u);
                    cur |= s2 & ((((cur >> (k + 2)) & 1u)) - 1u);
                    cur |= s3 & ((((cur >> (k + 3)) & 1u)) - 1u);
                }
                uint32 keep = ~cur;
                if (l == g) keepw = keep;
                if (gl + 1 < GPC) {
                    const uint4* sp = (const uint4*)(bp + (g + 1) * CHP + (gl + 1) * 32);
#pragma unroll
                    for (int q = 0; q < 8; ++q) sq[q] = sp[q];
                }
                uint32 upd = 0;
#pragma unroll
                for (int q = 0; q < 8; ++q) {
                    int k = q * 4;
                    upd |= rwq[q].x & (uint32)(((int)(keep << (31 - (k + 0)))) >> 31);
                    upd |= rwq[q].y & (uint32)(((int)(keep << (31 - (k + 1)))) >> 31);
                    upd |= rwq[q].z & (uint32)(((int)(keep << (31 - (k + 2)))) >> 31);
                    upd |= rwq[q].w & (uint32)(((int)(keep << (31 - (k + 3)))) >> 31);
                }
                supp |= upd;
            }
        }
        __syncthreads();
    }

    if (wv == 0) {
#pragma unroll
        for (int k = 0; k < 32; ++k)
            keepf[bt * TOPK + l * 32 + k] = (float)((keepw >> k) & 1u);
    }
}

extern "C" void kernel_launch(void* const* d_in, const int* in_sizes, int n_in,
                              void* d_out, int out_size, void* d_ws, size_t ws_size,
                              hipStream_t stream) {
    const float* inp     = (const float*)d_in[0];
    const float* anchors = (const float*)d_in[1];
    float* out   = (float*)d_out;                        // [B, N, 25]
    float* topf  = out  + (size_t)B * NCAND * CATTR;     // [B, 2048] indices as float
    float* keepf = topf + (size_t)B * TOPK;              // [B, 2048] 0/1 as float

    // workspace layout
    float*  cws = (float*)d_ws;                          // [B, NCAND] conf
    float*  pk  = cws + B * NCAND;                       // [B, NCAND, 8] packed geom
    float*  gx1 = pk  + (size_t)B * NCAND * 8;
    float*  gy1 = gx1 + B * TOPK;
    float*  gx2 = gy1 + B * TOPK;
    float*  gy2 = gx2 + B * TOPK;
    float*  gar = gy2 + B * TOPK;
    uint32* gcv = (uint32*)(gar + B * TOPK);
    uint32* rowmask = gcv + B * TOPK;                    // rmT: [B][64][2048] u32 = 8 MiB
    uint32* vwords  = rowmask + (size_t)B * TOPK * NWORD;
    // sort scratch aliases onto rowmask (sort completes before build writes)
    u64* runs = (u64*)rowmask;                           // 1 MiB

    decode_kernel<<<(B * NCAND) / 256, 256, 0, stream>>>(inp, anchors, out, cws, pk);
    sort1_kernel<<<B * 4, 256, 0, stream>>>(cws, runs);
    sort23_kernel<<<B, 256, 0, stream>>>(runs, topf);
    geo_kernel<<<(B * TOPK) / 256, 256, 0, stream>>>(pk, topf, gx1, gy1, gx2, gy2, gar, gcv, vwords);
    build_kernel<<<dim3(16, B), 1024, 0, stream>>>(gx1, gy1, gx2, gy2, gar, gcv, rowmask);
    scan_kernel<<<B, 1024, 0, stream>>>(rowmask, vwords, keepf);
}